// Round 3
// baseline (364.646 us; speedup 1.0000x reference)
//
#include <hip/hip_runtime.h>
#include <hip/hip_bf16.h>
#include <stdint.h>

#define BATCH 512
#define NN 32
#define T_IN 12
#define HID 64
#define HEADS 8
#define OUT_CH 9
#define EPB (NN*8)       // 256 edges per batch (before self loops)
#define ETOT (EPB+NN)    // 288 with self loops
#define F1 (HEADS*HID)   // 512

using u16 = unsigned short;
using u32 = unsigned int;

__device__ __forceinline__ float bf2f(u16 u){ return __uint_as_float(((u32)u)<<16); }
__device__ __forceinline__ u16 f2bf(float f){
    u32 x = __float_as_uint(f);
    u32 r = (x + 0x7FFFu + ((x>>16)&1u))>>16;
    return (u16)r;
}
__device__ __forceinline__ float lo2f(u32 p){ return __uint_as_float(p<<16); }
__device__ __forceinline__ float hi2f(u32 p){ return __uint_as_float(p & 0xFFFF0000u); }
__device__ __forceinline__ float elu1(float x){ return x > 0.f ? x : (__expf(x)-1.f); }
__device__ __forceinline__ float sigm(float x){ return 1.f/(1.f+__expf(-x)); }
__device__ __forceinline__ float tanh_(float x){ return 1.f - 2.f/(__expf(2.f*x)+1.f); }

// ------------------------------------------------ dtype detection (fp32 vs bf16)
__global__ __launch_bounds__(256) void k_detect(const u32* __restrict__ xw, int* __restrict__ flag){
    __shared__ int cnt;
    if(threadIdx.x==0) cnt=0;
    __syncthreads();
    int c=0;
    for(int i=threadIdx.x;i<4096;i+=256){
        u32 w=xw[i];
        if(w & 0x7FFFFFFFu){
            u32 el=(w>>7)&0xFFu;     // exponent of low-half-as-bf16
            if(el>=0x90u) c++;
        }
    }
    atomicAdd(&cnt,c);
    __syncthreads();
    if(threadIdx.x==0) *flag = (cnt>256) ? 1 : 0;   // 1 = fp32 inputs, 0 = bf16
}

// ------------------------------------------------ canonicalize inputs into ws
struct CvtDesc {
    const void* src[21];
    void*       dst[21];
    int         n[21];
    int         tobf[21];   // 1: dst is bf16(u16); 0: dst is fp32
};

__global__ __launch_bounds__(256) void k_convert(CvtDesc d, const int* __restrict__ flag){
    const int seg = blockIdx.x;
    const int f = *flag;
    const void* s = d.src[seg];
    const int n = d.n[seg];
    const int stride = gridDim.y*256;
    int i0 = blockIdx.y*256 + threadIdx.x;
    if(d.tobf[seg]){
        u16* o=(u16*)d.dst[seg];
        for(int i=i0;i<n;i+=stride)
            o[i] = f ? f2bf(((const float*)s)[i]) : ((const u16*)s)[i];
    } else {
        float* o=(float*)d.dst[seg];
        for(int i=i0;i<n;i+=stride)
            o[i] = f ? ((const float*)s)[i] : bf2f(((const u16*)s)[i]);
    }
}

// ---------------------------------------------------------------- GAT layer 1
__global__ __launch_bounds__(256) void k_gat1(
    const float* __restrict__ x, const int* __restrict__ ei,
    const float* __restrict__ W1, const float* __restrict__ a_s, const float* __restrict__ a_d,
    const float* __restrict__ b1, u16* __restrict__ h1g)
{
    const int b = blockIdx.x, t = threadIdx.x;
    __shared__ float s_x[NN][T_IN];
    __shared__ float s_W1[T_IN*F1];           // 24 KB fp32
    __shared__ u16  s_h[NN][514];             // padded rows, pre-bias h (bf16)
    __shared__ float s_es[NN][HEADS], s_ed[NN][HEADS];
    __shared__ unsigned char s_src[ETOT], s_dst[ETOT];
    __shared__ float s_al[ETOT][HEADS];
    __shared__ int s_cnt[NN], s_off[NN], s_fil[NN];
    __shared__ short s_lst[ETOT];

    for(int i=t;i<NN*T_IN;i+=256) s_x[i/T_IN][i%T_IN] = x[b*NN*T_IN + i];
    for(int i=t;i<T_IN*F1;i+=256) s_W1[i]=W1[i];
    if(t<EPB){
        s_src[t] = (unsigned char)(ei[b*EPB+t] - b*NN);
        s_dst[t] = (unsigned char)(ei[(size_t)BATCH*EPB + b*EPB+t] - b*NN);
    }
    if(t<NN){ s_src[EPB+t]=s_dst[EPB+t]=(unsigned char)t; s_cnt[t]=0; s_fil[t]=0; }
    __syncthreads();

    // h = x @ W1 (pre-bias) into LDS bf16
    for(int o=t;o<NN*F1;o+=256){
        int n=o>>9, j=o&511;
        float acc=0.f;
        #pragma unroll
        for(int k=0;k<T_IN;k++) acc += s_x[n][k]*s_W1[k*F1+j];
        s_h[n][j]=f2bf(acc);
    }
    for(int e=t;e<ETOT;e+=256) atomicAdd(&s_cnt[s_dst[e]],1);   // FIX: cover all 288
    __syncthreads();

    // es/ed per (node, head)
    {
        int n=t>>3, hd=t&7;
        float e1=0.f,e2=0.f;
        #pragma unroll
        for(int c=0;c<HID;c++){
            float hv = bf2f(s_h[n][hd*HID+c]);
            e1 += hv*a_s[hd*HID+c];
            e2 += hv*a_d[hd*HID+c];
        }
        s_es[n][hd]=e1; s_ed[n][hd]=e2;
    }
    if(t==0){ int o=0; for(int i=0;i<NN;i++){ s_off[i]=o; o+=s_cnt[i]; } }
    __syncthreads();

    // CSR fill + edge logits (leaky_relu 0.2)
    for(int e=t;e<ETOT;e+=256){                                  // FIX: cover all 288
        int d=s_dst[e]; int p=atomicAdd(&s_fil[d],1); s_lst[s_off[d]+p]=(short)e;
    }
    for(int e=t;e<ETOT;e+=256){
        int s=s_src[e], d=s_dst[e];
        #pragma unroll
        for(int hd=0;hd<HEADS;hd++){
            float v = s_es[s][hd]+s_ed[d][hd];
            s_al[e][hd] = v>0.f? v : 0.2f*v;
        }
    }
    __syncthreads();

    // per-(dst,head) softmax over incoming edges
    {
        int d=t>>3, hd=t&7;
        int o=s_off[d], c=s_cnt[d];
        float m=-1e30f;
        for(int i=0;i<c;i++) m = fmaxf(m, s_al[s_lst[o+i]][hd]);
        float ss=0.f;
        for(int i=0;i<c;i++){ int e=s_lst[o+i]; float p=__expf(s_al[e][hd]-m); s_al[e][hd]=p; ss+=p; }
        float inv = 1.f/(ss+1e-16f);
        for(int i=0;i<c;i++) s_al[s_lst[o+i]][hd]*=inv;
    }
    __syncthreads();

    // aggregate, +b1, ELU, store bf16
    {
        int d=t&31, hd=t>>5;
        int o=s_off[d], cnt=s_cnt[d];
        float acc[HID];
        #pragma unroll
        for(int c=0;c<HID;c++) acc[c]=0.f;
        for(int i=0;i<cnt;i++){
            int e=s_lst[o+i];
            float a=s_al[e][hd];
            int srow=s_src[e];
            const u32* hp = (const u32*)&s_h[srow][hd*HID];
            #pragma unroll
            for(int c2=0;c2<HID/2;c2++){
                u32 p = hp[c2];
                acc[2*c2]   += a*lo2f(p);
                acc[2*c2+1] += a*hi2f(p);
            }
        }
        size_t base = ((size_t)(b*NN+d))*F1 + hd*HID;
        u32* outp = (u32*)(h1g+base);
        #pragma unroll
        for(int c2=0;c2<HID/2;c2++){
            float v0 = elu1(acc[2*c2]   + b1[hd*HID+2*c2]);
            float v1 = elu1(acc[2*c2+1] + b1[hd*HID+2*c2+1]);
            outp[c2] = (u32)f2bf(v0) | ((u32)f2bf(v1)<<16);
        }
    }
}

// --------------------------------------------- GAT layer 2 + LayerNorm (+transpose)
__global__ __launch_bounds__(256) void k_gat2ln(
    const u16* __restrict__ h1g, const int* __restrict__ ei,
    const u16* __restrict__ W2, const float* __restrict__ a_s2, const float* __restrict__ a_d2,
    const float* __restrict__ b2, const float* __restrict__ gam, const float* __restrict__ bet,
    float* __restrict__ hlng)
{
    const int b=blockIdx.x, t=threadIdx.x;
    __shared__ u16 s_h1[NN*F1];        // 32 KB, [n][k] bf16 (post-ELU h1)
    __shared__ float s_h2[NN][HID];    // pre-bias gemm result
    __shared__ float s_es[NN], s_ed[NN];
    __shared__ unsigned char s_src[ETOT], s_dst[ETOT];
    __shared__ float s_al[ETOT];
    __shared__ int s_cnt[NN], s_off[NN], s_fil[NN];
    __shared__ short s_lst[ETOT];

    { const u32* g=(const u32*)(h1g + (size_t)b*NN*F1); u32* sp=(u32*)s_h1;
      for(int i=t;i<(NN*F1)/2;i+=256) sp[i]=g[i]; }
    if(t<EPB){
        s_src[t]=(unsigned char)(ei[b*EPB+t]-b*NN);
        s_dst[t]=(unsigned char)(ei[(size_t)BATCH*EPB+b*EPB+t]-b*NN);
    }
    if(t<NN){ s_src[EPB+t]=s_dst[EPB+t]=(unsigned char)t; s_cnt[t]=0; s_fil[t]=0; }
    __syncthreads();

    for(int e=t;e<ETOT;e+=256) atomicAdd(&s_cnt[s_dst[e]],1);   // FIX: cover all 288
    // GEMM h2 = h1 @ W2  (W2 bf16, streamed from L1/L2)
    {
        int c2=t&31, ng=t>>5;   // columns 2*c2,2*c2+1 ; rows ng*4..ng*4+3
        const u32* wp=(const u32*)W2;   // [512][32] u32 words
        const u32* r0=(const u32*)&s_h1[(ng*4+0)*F1];
        const u32* r1=(const u32*)&s_h1[(ng*4+1)*F1];
        const u32* r2=(const u32*)&s_h1[(ng*4+2)*F1];
        const u32* r3=(const u32*)&s_h1[(ng*4+3)*F1];
        float a00=0,a01=0,a10=0,a11=0,a20=0,a21=0,a30=0,a31=0;
        #pragma unroll 8
        for(int k2=0;k2<F1/2;k2++){
            u32 w0=wp[(2*k2)*32+c2], w1=wp[(2*k2+1)*32+c2];
            float wl0=lo2f(w0),wh0=hi2f(w0),wl1=lo2f(w1),wh1=hi2f(w1);
            u32 p0=r0[k2],p1=r1[k2],p2=r2[k2],p3=r3[k2];
            float e,f;
            e=lo2f(p0); f=hi2f(p0); a00+=e*wl0+f*wl1; a01+=e*wh0+f*wh1;
            e=lo2f(p1); f=hi2f(p1); a10+=e*wl0+f*wl1; a11+=e*wh0+f*wh1;
            e=lo2f(p2); f=hi2f(p2); a20+=e*wl0+f*wl1; a21+=e*wh0+f*wh1;
            e=lo2f(p3); f=hi2f(p3); a30+=e*wl0+f*wl1; a31+=e*wh0+f*wh1;
        }
        s_h2[ng*4+0][2*c2]=a00; s_h2[ng*4+0][2*c2+1]=a01;
        s_h2[ng*4+1][2*c2]=a10; s_h2[ng*4+1][2*c2+1]=a11;
        s_h2[ng*4+2][2*c2]=a20; s_h2[ng*4+2][2*c2+1]=a21;
        s_h2[ng*4+3][2*c2]=a30; s_h2[ng*4+3][2*c2+1]=a31;
    }
    __syncthreads();

    // es/ed (single head) via 8-lane shuffle reduce
    {
        int n=t>>3, g=t&7;
        float e1=0,e2=0;
        #pragma unroll
        for(int cc=0; cc<8; cc++){
            float hv = s_h2[n][g*8+cc];
            e1 += hv*a_s2[g*8+cc];
            e2 += hv*a_d2[g*8+cc];
        }
        #pragma unroll
        for(int m=1;m<8;m<<=1){ e1 += __shfl_xor(e1,m,64); e2 += __shfl_xor(e2,m,64); }
        if(g==0){ s_es[n]=e1; s_ed[n]=e2; }
    }
    if(t==0){ int o=0; for(int i=0;i<NN;i++){ s_off[i]=o; o+=s_cnt[i]; } }
    __syncthreads();

    for(int e=t;e<ETOT;e+=256){                                  // FIX: cover all 288
        int d=s_dst[e]; int p=atomicAdd(&s_fil[d],1); s_lst[s_off[d]+p]=(short)e;
    }
    for(int e=t;e<ETOT;e+=256){
        float v = s_es[s_src[e]] + s_ed[s_dst[e]];
        s_al[e] = v>0.f? v:0.2f*v;
    }
    __syncthreads();

    if(t<NN){
        int o=s_off[t], c=s_cnt[t];
        float m=-1e30f;
        for(int i=0;i<c;i++) m=fmaxf(m, s_al[s_lst[o+i]]);
        float ss=0;
        for(int i=0;i<c;i++){int e=s_lst[o+i]; float p=__expf(s_al[e]-m); s_al[e]=p; ss+=p;}
        float inv=1.f/(ss+1e-16f);
        for(int i=0;i<c;i++) s_al[s_lst[o+i]]*=inv;
    }
    __syncthreads();

    // aggregate + b2 + ELU + LayerNorm + transposed store [b][c][n]
    {
        int n=t>>3, g=t&7;
        float acc[8];
        #pragma unroll
        for(int i=0;i<8;i++) acc[i]=0;
        int o=s_off[n], cnt=s_cnt[n];
        for(int i=0;i<cnt;i++){
            int e=s_lst[o+i]; float a=s_al[e]; int sr=s_src[e];
            const float4* hp=(const float4*)&s_h2[sr][g*8];
            float4 v0=hp[0], v1=hp[1];
            acc[0]+=a*v0.x; acc[1]+=a*v0.y; acc[2]+=a*v0.z; acc[3]+=a*v0.w;
            acc[4]+=a*v1.x; acc[5]+=a*v1.y; acc[6]+=a*v1.z; acc[7]+=a*v1.w;
        }
        float sum=0,sq=0;
        #pragma unroll
        for(int i=0;i<8;i++){
            float v = elu1(acc[i] + b2[g*8+i]);
            acc[i]=v; sum+=v; sq+=v*v;
        }
        #pragma unroll
        for(int m=1;m<8;m<<=1){ sum+=__shfl_xor(sum,m,64); sq+=__shfl_xor(sq,m,64); }
        float mu = sum*(1.f/64.f);
        float var = sq*(1.f/64.f) - mu*mu;
        float rs = rsqrtf(var + 1e-5f);
        float* outp = hlng + (size_t)b*HID*NN;
        #pragma unroll
        for(int i=0;i<8;i++){
            int c=g*8+i;
            float v=(acc[i]-mu)*rs*gam[c] + bet[c];
            outp[c*NN + n] = v;
        }
    }
}

// ---------------------------------------------------------------- GRU layer 1
__global__ __launch_bounds__(192) void k_gru1(
    const float* __restrict__ hlng, const float* __restrict__ Wi, const float* __restrict__ Wh,
    const float* __restrict__ bi, const float* __restrict__ bh, float* __restrict__ y1g)
{
    const int b=blockIdx.x, t=threadIdx.x;
    __shared__ float s_x[64][32];   // [time=channel][node]
    __shared__ float s_h[HID];
    __shared__ float s_gi[192], s_gh[192];

    for(int i=t;i<64*32;i+=192) ((float*)s_x)[i]=hlng[(size_t)b*2048+i];
    if(t<HID) s_h[t]=0.f;
    float wi[32], wh[64];
    {
        const float4* wp=(const float4*)(Wi + t*32);
        #pragma unroll
        for(int k=0;k<8;k++){ float4 v=wp[k]; wi[4*k]=v.x; wi[4*k+1]=v.y; wi[4*k+2]=v.z; wi[4*k+3]=v.w; }
        const float4* hp=(const float4*)(Wh + t*64);
        #pragma unroll
        for(int k=0;k<16;k++){ float4 v=hp[k]; wh[4*k]=v.x; wh[4*k+1]=v.y; wh[4*k+2]=v.z; wh[4*k+3]=v.w; }
    }
    float bii=bi[t], bhh=bh[t];
    __syncthreads();

    for(int tt=0; tt<64; tt++){
        float ai=bii;
        const float4* xp=(const float4*)s_x[tt];
        #pragma unroll
        for(int k4=0;k4<8;k4++){
            float4 v=xp[k4];
            ai += wi[4*k4]*v.x + wi[4*k4+1]*v.y + wi[4*k4+2]*v.z + wi[4*k4+3]*v.w;
        }
        float ah=bhh;
        const float4* hp=(const float4*)s_h;
        #pragma unroll
        for(int k4=0;k4<16;k4++){
            float4 v=hp[k4];
            ah += wh[4*k4]*v.x + wh[4*k4+1]*v.y + wh[4*k4+2]*v.z + wh[4*k4+3]*v.w;
        }
        s_gi[t]=ai; s_gh[t]=ah;
        __syncthreads();
        if(t<HID){
            float r=sigm(s_gi[t]+s_gh[t]);
            float z=sigm(s_gi[64+t]+s_gh[64+t]);
            float n_=tanh_(s_gi[128+t]+r*s_gh[128+t]);
            float h=(1.f-z)*n_+z*s_h[t];
            s_h[t]=h;
            y1g[(size_t)b*4096 + tt*64 + t]=h;
        }
        __syncthreads();
    }
}

// ------------------------------------------------------- GRU layer 2 + final FC
__global__ __launch_bounds__(192) void k_gru2(
    const float* __restrict__ y1g, const float* __restrict__ Wi, const float* __restrict__ Wh,
    const float* __restrict__ bi, const float* __restrict__ bh,
    const float* __restrict__ Wf, const float* __restrict__ bfv,
    void* __restrict__ outp, const int* __restrict__ flag)
{
    const int b=blockIdx.x, t=threadIdx.x;
    __shared__ float s_y[64][HID];
    __shared__ float s_h[HID];
    __shared__ float s_gi[192], s_gh[192];

    for(int i=t;i<64*HID;i+=192) ((float*)s_y)[i]=y1g[(size_t)b*4096+i];
    if(t<HID) s_h[t]=0.f;
    float wi[64], wh[64];
    {
        const float4* wp=(const float4*)(Wi + t*64);
        #pragma unroll
        for(int k=0;k<16;k++){ float4 v=wp[k]; wi[4*k]=v.x; wi[4*k+1]=v.y; wi[4*k+2]=v.z; wi[4*k+3]=v.w; }
        const float4* hp=(const float4*)(Wh + t*64);
        #pragma unroll
        for(int k=0;k<16;k++){ float4 v=hp[k]; wh[4*k]=v.x; wh[4*k+1]=v.y; wh[4*k+2]=v.z; wh[4*k+3]=v.w; }
    }
    float bii=bi[t], bhh=bh[t];
    __syncthreads();

    for(int tt=0;tt<64;tt++){
        float ai=bii, ah=bhh;
        const float4* xp=(const float4*)s_y[tt];
        const float4* hp=(const float4*)s_h;
        #pragma unroll
        for(int k4=0;k4<16;k4++){
            float4 xv=xp[k4], hv=hp[k4];
            ai += wi[4*k4]*xv.x + wi[4*k4+1]*xv.y + wi[4*k4+2]*xv.z + wi[4*k4+3]*xv.w;
            ah += wh[4*k4]*hv.x + wh[4*k4+1]*hv.y + wh[4*k4+2]*hv.z + wh[4*k4+3]*hv.w;
        }
        s_gi[t]=ai; s_gh[t]=ah;
        __syncthreads();
        if(t<HID){
            float r=sigm(s_gi[t]+s_gh[t]);
            float z=sigm(s_gi[64+t]+s_gh[64+t]);
            float n_=tanh_(s_gi[128+t]+r*s_gh[128+t]);
            float h=(1.f-z)*n_+z*s_h[t];
            s_h[t]=h;
        }
        __syncthreads();
    }
    if(t<OUT_CH){
        float acc=bfv[t];
        #pragma unroll
        for(int i=0;i<HID;i++) acc += s_h[i]*Wf[t*HID+i];
        if(*flag) ((float*)outp)[b*OUT_CH+t]=acc;
        else      ((u16*)outp)[b*OUT_CH+t]=f2bf(acc);
    }
}

extern "C" void kernel_launch(void* const* d_in, const int* in_sizes, int n_in,
                              void* d_out, int out_size, void* d_ws, size_t ws_size,
                              hipStream_t stream)
{
    char* ws=(char*)d_ws;
    int* flag = (int*)ws;
    float* cf = (float*)(ws + 256);
    float* c_x   = cf; cf+=196608;
    float* c_W1  = cf; cf+=6144;
    float* c_as1 = cf; cf+=512;
    float* c_ad1 = cf; cf+=512;
    float* c_b1  = cf; cf+=512;
    float* c_as2 = cf; cf+=64;
    float* c_ad2 = cf; cf+=64;
    float* c_b2  = cf; cf+=64;
    float* c_gam = cf; cf+=64;
    float* c_bet = cf; cf+=64;
    float* c_Wi1 = cf; cf+=6144;
    float* c_Wh1 = cf; cf+=12288;
    float* c_bi1 = cf; cf+=192;
    float* c_bh1 = cf; cf+=192;
    float* c_Wi2 = cf; cf+=12288;
    float* c_Wh2 = cf; cf+=12288;
    float* c_bi2 = cf; cf+=192;
    float* c_bh2 = cf; cf+=192;
    float* c_Wf  = cf; cf+=576;
    float* c_bf  = cf; cf+=9;
    uintptr_t p = ((uintptr_t)cf + 255) & ~(uintptr_t)255;
    u16* c_W2 = (u16*)p;                         // 32768 bf16 = 64 KB
    p = (p + 32768*2 + 255) & ~(uintptr_t)255;
    u16* h1g = (u16*)p;                          // 512*32*512 bf16 = 16.78 MB
    p = (p + (size_t)BATCH*NN*F1*2 + 255) & ~(uintptr_t)255;
    float* hlng = (float*)p;                     // 512*64*32 f32 = 4.19 MB
    p = (p + (size_t)BATCH*HID*NN*4 + 255) & ~(uintptr_t)255;
    float* y1g = (float*)p;                      // 512*64*64 f32 = 8.39 MB

    const int* ei = (const int*)d_in[1];

    CvtDesc d;
    const int srcIdx[21] = {0,2,3,4,5,6,7,8,9,10,11,12,13,14,15,16,17,18,19,20,21};
    void* dsts[21] = {c_x,c_W1,c_as1,c_ad1,c_b1,(void*)c_W2,c_as2,c_ad2,c_b2,c_gam,c_bet,
                      c_Wi1,c_Wh1,c_bi1,c_bh1,c_Wi2,c_Wh2,c_bi2,c_bh2,c_Wf,c_bf};
    const int ns[21] = {196608,6144,512,512,512,32768,64,64,64,64,64,
                        6144,12288,192,192,12288,12288,192,192,576,9};
    for(int i=0;i<21;i++){
        d.src[i]=d_in[srcIdx[i]];
        d.dst[i]=dsts[i];
        d.n[i]=ns[i];
        d.tobf[i]=(i==5)?1:0;   // W2 -> bf16
    }

    k_detect <<<dim3(1),dim3(256),0,stream>>>((const u32*)d_in[0], flag);
    k_convert<<<dim3(21,8),dim3(256),0,stream>>>(d, flag);
    k_gat1   <<<dim3(BATCH),dim3(256),0,stream>>>(c_x,ei,c_W1,c_as1,c_ad1,c_b1,h1g);
    k_gat2ln <<<dim3(BATCH),dim3(256),0,stream>>>(h1g,ei,c_W2,c_as2,c_ad2,c_b2,c_gam,c_bet,hlng);
    k_gru1   <<<dim3(BATCH),dim3(192),0,stream>>>(hlng,c_Wi1,c_Wh1,c_bi1,c_bh1,y1g);
    k_gru2   <<<dim3(BATCH),dim3(192),0,stream>>>(y1g,c_Wi2,c_Wh2,c_bi2,c_bh2,c_Wf,c_bf,d_out,flag);
}

// Round 4
// 287.314 us; speedup vs baseline: 1.2692x; 1.2692x over previous
//
#include <hip/hip_runtime.h>
#include <hip/hip_bf16.h>
#include <stdint.h>

#define BATCH 512
#define NN 32
#define T_IN 12
#define HID 64
#define HEADS 8
#define OUT_CH 9
#define EPB (NN*8)       // 256 edges per batch (before self loops)
#define ETOT (EPB+NN)    // 288 with self loops
#define F1 (HEADS*HID)   // 512

using u16 = unsigned short;
using u32 = unsigned int;
typedef _Float16 f16;
typedef _Float16 f16x2 __attribute__((ext_vector_type(2)));

__device__ __forceinline__ float bf2f(u16 u){ return __uint_as_float(((u32)u)<<16); }
__device__ __forceinline__ u16 f2bf(float f){
    u32 x = __float_as_uint(f);
    u32 r = (x + 0x7FFFu + ((x>>16)&1u))>>16;
    return (u16)r;
}
__device__ __forceinline__ u32 packf16(float a, float b){
    f16x2 p; p.x=(f16)a; p.y=(f16)b; return __builtin_bit_cast(u32,p);
}
__device__ __forceinline__ u16 f2h16(float a){ f16 h=(f16)a; return __builtin_bit_cast(u16,h); }
__device__ __forceinline__ float lof(u32 w){ return (float)__builtin_bit_cast(f16x2,w).x; }
__device__ __forceinline__ float hif(u32 w){ return (float)__builtin_bit_cast(f16x2,w).y; }
__device__ __forceinline__ float dot2(u32 a, u32 b, float c){
#if __has_builtin(__builtin_amdgcn_fdot2)
    return __builtin_amdgcn_fdot2(__builtin_bit_cast(f16x2,a), __builtin_bit_cast(f16x2,b), c, false);
#else
    return fmaf(lof(a),lof(b), fmaf(hif(a),hif(b), c));
#endif
}
__device__ __forceinline__ float elu1(float x){ return x > 0.f ? x : (__expf(x)-1.f); }
__device__ __forceinline__ float sigm(float x){ return 1.f/(1.f+__expf(-x)); }
__device__ __forceinline__ float tanh_(float x){ return 1.f - 2.f/(__expf(2.f*x)+1.f); }

// ------------------------------------------------ dtype detection (fp32 vs bf16)
__global__ __launch_bounds__(256) void k_detect(const u32* __restrict__ xw, int* __restrict__ flag){
    __shared__ int cnt;
    if(threadIdx.x==0) cnt=0;
    __syncthreads();
    int c=0;
    for(int i=threadIdx.x;i<4096;i+=256){
        u32 w=xw[i];
        if(w & 0x7FFFFFFFu){
            u32 el=(w>>7)&0xFFu;
            if(el>=0x90u) c++;
        }
    }
    atomicAdd(&cnt,c);
    __syncthreads();
    if(threadIdx.x==0) *flag = (cnt>256) ? 1 : 0;   // 1 = fp32 inputs, 0 = bf16
}

// ------------------------------------------------ canonicalize inputs into ws (fp32)
struct CvtDesc {
    const void* src[20];
    void*       dst[20];
    int         n[20];
};

__global__ __launch_bounds__(256) void k_convert(CvtDesc d, const int* __restrict__ flag){
    const int seg = blockIdx.x;
    const int f = *flag;
    const void* s = d.src[seg];
    const int n = d.n[seg];
    const int stride = gridDim.y*256;
    float* o=(float*)d.dst[seg];
    for(int i=blockIdx.y*256+threadIdx.x;i<n;i+=stride)
        o[i] = f ? ((const float*)s)[i] : bf2f(((const u16*)s)[i]);
}

// W2 [512][64] -> interleaved fp16 W2i[(k>>3)*64+j][k&7]
__global__ __launch_bounds__(256) void k_w2i(const void* __restrict__ W2src, u16* __restrict__ W2i,
                                             const int* __restrict__ flag){
    int i = blockIdx.x*256+threadIdx.x;            // i = k*64+j
    int k=i>>6, j=i&63;
    float v = (*flag)? ((const float*)W2src)[i] : bf2f(((const u16*)W2src)[i]);
    W2i[ (((size_t)(k>>3)*64 + j)<<3) + (k&7) ] = f2h16(v);
}

// ---------------------------------------------------------------- GAT layer 1
__global__ __launch_bounds__(256,2) void k_gat1(
    const float* __restrict__ x, const int* __restrict__ ei,
    const float* __restrict__ W1, const float* __restrict__ a_s, const float* __restrict__ a_d,
    const float* __restrict__ b1, u32* __restrict__ h1g)
{
    const int b = blockIdx.x, t = threadIdx.x;
    __shared__ __align__(16) float s_x[NN][12];
    __shared__ float s_W1[T_IN*F1];
    __shared__ __align__(16) u16 s_h[NN][520];     // fp16, row pad 8 (16B-aligned rows)
    __shared__ u32 s_aspk[HEADS*32], s_adpk[HEADS*32];
    __shared__ float s_es[NN][HEADS], s_ed[NN][HEADS];
    __shared__ unsigned char s_src[ETOT], s_dst[ETOT];
    __shared__ float s_al[ETOT][HEADS];
    __shared__ int s_cnt[NN], s_off[NN], s_fil[NN];
    __shared__ short s_lst[ETOT];

    for(int i=t;i<NN*T_IN;i+=256) s_x[i/12][i%12] = x[b*NN*T_IN + i];
    for(int i=t;i<T_IN*F1;i+=256) s_W1[i]=W1[i];
    s_aspk[t]=packf16(a_s[2*t],a_s[2*t+1]);
    s_adpk[t]=packf16(a_d[2*t],a_d[2*t+1]);
    if(t<EPB){
        s_src[t] = (unsigned char)(ei[b*EPB+t] - b*NN);
        s_dst[t] = (unsigned char)(ei[(size_t)BATCH*EPB + b*EPB+t] - b*NN);
    }
    if(t<NN){ s_src[EPB+t]=s_dst[EPB+t]=(unsigned char)t; s_cnt[t]=0; s_fil[t]=0; }
    __syncthreads();

    // h = x @ W1 (pre-bias) -> LDS fp16 ; thread t owns columns t and t+256
    {
        float w0[12], w1[12];
        #pragma unroll
        for(int k=0;k<12;k++){ w0[k]=s_W1[k*F1+t]; w1[k]=s_W1[k*F1+t+256]; }
        for(int n=0;n<NN;n++){
            float xr[12];
            const float4* xp=(const float4*)s_x[n];
            *(float4*)&xr[0]=xp[0]; *(float4*)&xr[4]=xp[1]; *(float4*)&xr[8]=xp[2];
            float A=0.f,B=0.f;
            #pragma unroll
            for(int k=0;k<12;k++){ A=fmaf(xr[k],w0[k],A); B=fmaf(xr[k],w1[k],B); }
            s_h[n][t]=f2h16(A); s_h[n][t+256]=f2h16(B);
        }
    }
    for(int e=t;e<ETOT;e+=256) atomicAdd(&s_cnt[s_dst[e]],1);
    __syncthreads();

    // es/ed per (node, head) via fp16 dot2
    {
        int n=t&31, hd=t>>5;
        const uint4* hp=(const uint4*)((const u16*)s_h[n] + hd*64);
        u32 hw[32];
        #pragma unroll
        for(int q=0;q<8;q++) *(uint4*)&hw[q*4]=hp[q];
        float e1=0.f,e2=0.f;
        #pragma unroll
        for(int k=0;k<32;k++){ e1=dot2(hw[k],s_aspk[hd*32+k],e1); e2=dot2(hw[k],s_adpk[hd*32+k],e2); }
        s_es[n][hd]=e1; s_ed[n][hd]=e2;
    }
    if(t==0){ int o=0; for(int i=0;i<NN;i++){ s_off[i]=o; o+=s_cnt[i]; } }
    __syncthreads();

    for(int e=t;e<ETOT;e+=256){
        int d=s_dst[e]; int p=atomicAdd(&s_fil[d],1); s_lst[s_off[d]+p]=(short)e;
    }
    for(int e=t;e<ETOT;e+=256){
        int s=s_src[e], d=s_dst[e];
        #pragma unroll
        for(int hd=0;hd<HEADS;hd++){
            float v = s_es[s][hd]+s_ed[d][hd];
            s_al[e][hd] = v>0.f? v : 0.2f*v;
        }
    }
    __syncthreads();

    // per-(dst,head) softmax
    {
        int d=t>>3, hd=t&7;
        int o=s_off[d], c=s_cnt[d];
        float m=-1e30f;
        for(int i=0;i<c;i++) m = fmaxf(m, s_al[s_lst[o+i]][hd]);
        float ss=0.f;
        for(int i=0;i<c;i++){ int e=s_lst[o+i]; float p=__expf(s_al[e][hd]-m); s_al[e][hd]=p; ss+=p; }
        float inv = 1.f/(ss+1e-16f);
        for(int i=0;i<c;i++) s_al[s_lst[o+i]][hd]*=inv;
    }
    __syncthreads();

    // aggregate in 4 column-chunks of 16 (acc[16] stays in regs), +b1, ELU, store fp16-packed
    {
        int d=t&31, hd=t>>5;
        int o=s_off[d], cnt=s_cnt[d];
        size_t obase = ((size_t)(b*NN+d))*256 + hd*32;
        #pragma unroll
        for(int ch=0;ch<4;ch++){
            float acc[16];
            #pragma unroll
            for(int i=0;i<16;i++) acc[i]=0.f;
            for(int i=0;i<cnt;i++){
                int e=s_lst[o+i]; float a=s_al[e][hd]; int sr=s_src[e];
                const uint4* hp=(const uint4*)((const u16*)s_h[sr] + hd*64 + ch*16);
                u32 pw[8];
                *(uint4*)&pw[0]=hp[0]; *(uint4*)&pw[4]=hp[1];
                #pragma unroll
                for(int q=0;q<8;q++){ acc[2*q]+=a*lof(pw[q]); acc[2*q+1]+=a*hif(pw[q]); }
            }
            u32* op = h1g + obase + ch*8;
            #pragma unroll
            for(int j=0;j<8;j++){
                float v0=elu1(acc[2*j]   + b1[hd*64+ch*16+2*j]);
                float v1=elu1(acc[2*j+1] + b1[hd*64+ch*16+2*j+1]);
                op[j]=packf16(v0,v1);
            }
        }
    }
}

// --------------------------------------------- GAT layer 2 + LayerNorm (+transpose)
__global__ __launch_bounds__(256,2) void k_gat2ln(
    const u32* __restrict__ h1g, const int* __restrict__ ei,
    const uint4* __restrict__ W2i, const float* __restrict__ a_s2, const float* __restrict__ a_d2,
    const float* __restrict__ b2, const float* __restrict__ gam, const float* __restrict__ bet,
    float* __restrict__ hlng)
{
    const int b=blockIdx.x, t=threadIdx.x;
    __shared__ __align__(16) u32 s_h1[NN*260];   // fp16-packed rows, padded to 260 u32
    __shared__ float s_h2[NN][HID];
    __shared__ float s_es[NN], s_ed[NN];
    __shared__ unsigned char s_src[ETOT], s_dst[ETOT];
    __shared__ float s_al[ETOT];
    __shared__ int s_cnt[NN], s_off[NN], s_fil[NN];
    __shared__ short s_lst[ETOT];

    { const u32* g = h1g + (size_t)b*8192;
      for(int w=t; w<8192; w+=256){ int n=w>>8, c=w&255; s_h1[n*260+c]=g[w]; } }
    if(t<EPB){
        s_src[t]=(unsigned char)(ei[b*EPB+t]-b*NN);
        s_dst[t]=(unsigned char)(ei[(size_t)BATCH*EPB+b*EPB+t]-b*NN);
    }
    if(t<NN){ s_src[EPB+t]=s_dst[EPB+t]=(unsigned char)t; s_cnt[t]=0; s_fil[t]=0; }
    __syncthreads();

    for(int e=t;e<ETOT;e+=256) atomicAdd(&s_cnt[s_dst[e]],1);
    // GEMM h2 = h1 @ W2 : 2 rows x 4 cols per thread, fp16 dot2, W2 interleaved from global
    {
        int n0=(t>>4)<<1, j0=(t&15)<<2;
        const u32* r0=&s_h1[n0*260];
        const u32* r1=&s_h1[(n0+1)*260];
        float a00=0,a01=0,a02=0,a03=0,a10=0,a11=0,a12=0,a13=0;
        for(int kb=0;kb<64;kb++){
            uint4 A0=*(const uint4*)&r0[kb*4];
            uint4 A1=*(const uint4*)&r1[kb*4];
            const uint4* wp=&W2i[kb*64+j0];
            uint4 w0=wp[0], w1=wp[1], w2=wp[2], w3=wp[3];
            a00=dot2(A0.x,w0.x,a00); a00=dot2(A0.y,w0.y,a00); a00=dot2(A0.z,w0.z,a00); a00=dot2(A0.w,w0.w,a00);
            a01=dot2(A0.x,w1.x,a01); a01=dot2(A0.y,w1.y,a01); a01=dot2(A0.z,w1.z,a01); a01=dot2(A0.w,w1.w,a01);
            a02=dot2(A0.x,w2.x,a02); a02=dot2(A0.y,w2.y,a02); a02=dot2(A0.z,w2.z,a02); a02=dot2(A0.w,w2.w,a02);
            a03=dot2(A0.x,w3.x,a03); a03=dot2(A0.y,w3.y,a03); a03=dot2(A0.z,w3.z,a03); a03=dot2(A0.w,w3.w,a03);
            a10=dot2(A1.x,w0.x,a10); a10=dot2(A1.y,w0.y,a10); a10=dot2(A1.z,w0.z,a10); a10=dot2(A1.w,w0.w,a10);
            a11=dot2(A1.x,w1.x,a11); a11=dot2(A1.y,w1.y,a11); a11=dot2(A1.z,w1.z,a11); a11=dot2(A1.w,w1.w,a11);
            a12=dot2(A1.x,w2.x,a12); a12=dot2(A1.y,w2.y,a12); a12=dot2(A1.z,w2.z,a12); a12=dot2(A1.w,w2.w,a12);
            a13=dot2(A1.x,w3.x,a13); a13=dot2(A1.y,w3.y,a13); a13=dot2(A1.z,w3.z,a13); a13=dot2(A1.w,w3.w,a13);
        }
        s_h2[n0][j0]=a00; s_h2[n0][j0+1]=a01; s_h2[n0][j0+2]=a02; s_h2[n0][j0+3]=a03;
        s_h2[n0+1][j0]=a10; s_h2[n0+1][j0+1]=a11; s_h2[n0+1][j0+2]=a12; s_h2[n0+1][j0+3]=a13;
    }
    __syncthreads();

    // es/ed (single head) via 8-lane shuffle reduce
    {
        int n=t>>3, g=t&7;
        float e1=0,e2=0;
        #pragma unroll
        for(int cc=0; cc<8; cc++){
            float hv = s_h2[n][g*8+cc];
            e1 += hv*a_s2[g*8+cc];
            e2 += hv*a_d2[g*8+cc];
        }
        #pragma unroll
        for(int m=1;m<8;m<<=1){ e1 += __shfl_xor(e1,m,64); e2 += __shfl_xor(e2,m,64); }
        if(g==0){ s_es[n]=e1; s_ed[n]=e2; }
    }
    if(t==0){ int o=0; for(int i=0;i<NN;i++){ s_off[i]=o; o+=s_cnt[i]; } }
    __syncthreads();

    for(int e=t;e<ETOT;e+=256){
        int d=s_dst[e]; int p=atomicAdd(&s_fil[d],1); s_lst[s_off[d]+p]=(short)e;
    }
    for(int e=t;e<ETOT;e+=256){
        float v = s_es[s_src[e]] + s_ed[s_dst[e]];
        s_al[e] = v>0.f? v:0.2f*v;
    }
    __syncthreads();

    if(t<NN){
        int o=s_off[t], c=s_cnt[t];
        float m=-1e30f;
        for(int i=0;i<c;i++) m=fmaxf(m, s_al[s_lst[o+i]]);
        float ss=0;
        for(int i=0;i<c;i++){int e=s_lst[o+i]; float p=__expf(s_al[e]-m); s_al[e]=p; ss+=p;}
        float inv=1.f/(ss+1e-16f);
        for(int i=0;i<c;i++) s_al[s_lst[o+i]]*=inv;
    }
    __syncthreads();

    // aggregate + b2 + ELU + LayerNorm + transposed store [b][c][n]
    {
        int n=t>>3, g=t&7;
        float acc[8];
        #pragma unroll
        for(int i=0;i<8;i++) acc[i]=0;
        int o=s_off[n], cnt=s_cnt[n];
        for(int i=0;i<cnt;i++){
            int e=s_lst[o+i]; float a=s_al[e]; int sr=s_src[e];
            const float4* hp=(const float4*)&s_h2[sr][g*8];
            float4 v0=hp[0], v1=hp[1];
            acc[0]+=a*v0.x; acc[1]+=a*v0.y; acc[2]+=a*v0.z; acc[3]+=a*v0.w;
            acc[4]+=a*v1.x; acc[5]+=a*v1.y; acc[6]+=a*v1.z; acc[7]+=a*v1.w;
        }
        float sum=0,sq=0;
        #pragma unroll
        for(int i=0;i<8;i++){
            float v = elu1(acc[i] + b2[g*8+i]);
            acc[i]=v; sum+=v; sq+=v*v;
        }
        #pragma unroll
        for(int m=1;m<8;m<<=1){ sum+=__shfl_xor(sum,m,64); sq+=__shfl_xor(sq,m,64); }
        float mu = sum*(1.f/64.f);
        float var = sq*(1.f/64.f) - mu*mu;
        float rs = rsqrtf(var + 1e-5f);
        float* outp = hlng + (size_t)b*HID*NN;
        #pragma unroll
        for(int i=0;i<8;i++){
            int c=g*8+i;
            float v=(acc[i]-mu)*rs*gam[c] + bet[c];
            outp[c*NN + n] = v;
        }
    }
}

// ---------------------------------------------------------------- GRU layer 1
// 64 threads = 1 wave; thread t owns gate rows {t, 64+t, 128+t} and hidden unit t.
__global__ __launch_bounds__(64,1) void k_gru1(
    const float* __restrict__ hlng, const float* __restrict__ Wi, const float* __restrict__ Wh,
    const float* __restrict__ bi, const float* __restrict__ bh, u16* __restrict__ y1g)
{
    const int b=blockIdx.x, t=threadIdx.x;
    __shared__ __align__(16) u32 s_xw[64*16];   // fp16-packed [t][32 feats]
    __shared__ __align__(16) u32 s_hw[32];      // fp16-packed h (64 vals)

    {   const float2* g=(const float2*)(hlng + (size_t)b*2048);
        for(int w=t;w<1024;w+=64){ float2 v=g[w]; s_xw[w]=packf16(v.x,v.y); } }

    u32 wir[16],wiz[16],win[16],whr[32],whz[32],whn[32];
    {
        const float2* WiF=(const float2*)Wi;
        const float2* WhF=(const float2*)Wh;
        #pragma unroll
        for(int k=0;k<16;k++){
            float2 a=WiF[t*16+k], c=WiF[(64+t)*16+k], d=WiF[(128+t)*16+k];
            wir[k]=packf16(a.x,a.y); wiz[k]=packf16(c.x,c.y); win[k]=packf16(d.x,d.y);
        }
        #pragma unroll
        for(int k=0;k<32;k++){
            float2 a=WhF[t*32+k], c=WhF[(64+t)*32+k], d=WhF[(128+t)*32+k];
            whr[k]=packf16(a.x,a.y); whz[k]=packf16(c.x,c.y); whn[k]=packf16(d.x,d.y);
        }
    }
    float br=bi[t]+bh[t], bz=bi[64+t]+bh[64+t], bxn=bi[128+t], bhn=bh[128+t];
    float h_cur=0.f;
    if(t<32) s_hw[t]=0u;
    __syncthreads();

    u16* yo = y1g + (size_t)b*4096;
    for(int tt=0;tt<64;tt++){
        u32 xw[16], hw[32];
        const uint4* xp=(const uint4*)&s_xw[tt*16];
        #pragma unroll
        for(int q=0;q<4;q++) *(uint4*)&xw[q*4]=xp[q];
        const uint4* hp=(const uint4*)s_hw;
        #pragma unroll
        for(int q=0;q<8;q++) *(uint4*)&hw[q*4]=hp[q];
        float ar=br, az=bz, axn=bxn, ahn=bhn;
        #pragma unroll
        for(int k=0;k<16;k++){ ar=dot2(xw[k],wir[k],ar); az=dot2(xw[k],wiz[k],az); axn=dot2(xw[k],win[k],axn); }
        #pragma unroll
        for(int k=0;k<32;k++){ ar=dot2(hw[k],whr[k],ar); az=dot2(hw[k],whz[k],az); ahn=dot2(hw[k],whn[k],ahn); }
        float r=sigm(ar), z=sigm(az), n=tanh_(axn + r*ahn);
        h_cur=(1.f-z)*n + z*h_cur;
        yo[tt*64+t]=f2h16(h_cur);
        __syncthreads();
        ((u16*)s_hw)[t]=f2h16(h_cur);
        __syncthreads();
    }
}

// ------------------------------------------------------- GRU layer 2 + final FC
__global__ __launch_bounds__(64,1) void k_gru2(
    const u16* __restrict__ y1g, const float* __restrict__ Wi, const float* __restrict__ Wh,
    const float* __restrict__ bi, const float* __restrict__ bh,
    const float* __restrict__ Wf, const float* __restrict__ bfv,
    void* __restrict__ outp, const int* __restrict__ flag)
{
    const int b=blockIdx.x, t=threadIdx.x;
    __shared__ __align__(16) u32 s_xw[64*32];   // fp16-packed [t][64 feats]
    __shared__ __align__(16) u32 s_hw[32];
    __shared__ float s_hf[64];

    {   const u32* g=(const u32*)(y1g + (size_t)b*4096);
        for(int w=t;w<2048;w+=64) s_xw[w]=g[w]; }

    u32 wir[32],wiz[32],win[32],whr[32],whz[32],whn[32];
    {
        const float2* WiF=(const float2*)Wi;
        const float2* WhF=(const float2*)Wh;
        #pragma unroll
        for(int k=0;k<32;k++){
            float2 a=WiF[t*32+k], c=WiF[(64+t)*32+k], d=WiF[(128+t)*32+k];
            wir[k]=packf16(a.x,a.y); wiz[k]=packf16(c.x,c.y); win[k]=packf16(d.x,d.y);
            float2 e=WhF[t*32+k], f=WhF[(64+t)*32+k], g2=WhF[(128+t)*32+k];
            whr[k]=packf16(e.x,e.y); whz[k]=packf16(f.x,f.y); whn[k]=packf16(g2.x,g2.y);
        }
    }
    float br=bi[t]+bh[t], bz=bi[64+t]+bh[64+t], bxn=bi[128+t], bhn=bh[128+t];
    float h_cur=0.f;
    if(t<32) s_hw[t]=0u;
    __syncthreads();

    for(int tt=0;tt<64;tt++){
        u32 xw[32], hw[32];
        const uint4* xp=(const uint4*)&s_xw[tt*32];
        #pragma unroll
        for(int q=0;q<8;q++) *(uint4*)&xw[q*4]=xp[q];
        const uint4* hp=(const uint4*)s_hw;
        #pragma unroll
        for(int q=0;q<8;q++) *(uint4*)&hw[q*4]=hp[q];
        float ar=br, az=bz, axn=bxn, ahn=bhn;
        #pragma unroll
        for(int k=0;k<32;k++){
            ar=dot2(xw[k],wir[k],ar); az=dot2(xw[k],wiz[k],az); axn=dot2(xw[k],win[k],axn);
            ar=dot2(hw[k],whr[k],ar); az=dot2(hw[k],whz[k],az); ahn=dot2(hw[k],whn[k],ahn);
        }
        float r=sigm(ar), z=sigm(az), n=tanh_(axn + r*ahn);
        h_cur=(1.f-z)*n + z*h_cur;
        __syncthreads();
        ((u16*)s_hw)[t]=f2h16(h_cur);
        __syncthreads();
    }
    s_hf[t]=h_cur;
    __syncthreads();
    if(t<OUT_CH){
        float acc=bfv[t];
        #pragma unroll
        for(int i=0;i<64;i++) acc += s_hf[i]*Wf[t*64+i];
        if(*flag) ((float*)outp)[b*OUT_CH+t]=acc;
        else      ((u16*)outp)[b*OUT_CH+t]=f2bf(acc);
    }
}

extern "C" void kernel_launch(void* const* d_in, const int* in_sizes, int n_in,
                              void* d_out, int out_size, void* d_ws, size_t ws_size,
                              hipStream_t stream)
{
    char* ws=(char*)d_ws;
    int* flag = (int*)ws;
    float* cf = (float*)(ws + 256);
    float* c_x   = cf; cf+=196608;
    float* c_W1  = cf; cf+=6144;
    float* c_as1 = cf; cf+=512;
    float* c_ad1 = cf; cf+=512;
    float* c_b1  = cf; cf+=512;
    float* c_as2 = cf; cf+=64;
    float* c_ad2 = cf; cf+=64;
    float* c_b2  = cf; cf+=64;
    float* c_gam = cf; cf+=64;
    float* c_bet = cf; cf+=64;
    float* c_Wi1 = cf; cf+=6144;
    float* c_Wh1 = cf; cf+=12288;
    float* c_bi1 = cf; cf+=192;
    float* c_bh1 = cf; cf+=192;
    float* c_Wi2 = cf; cf+=12288;
    float* c_Wh2 = cf; cf+=12288;
    float* c_bi2 = cf; cf+=192;
    float* c_bh2 = cf; cf+=192;
    float* c_Wf  = cf; cf+=576;
    float* c_bf  = cf; cf+=9;
    uintptr_t p = ((uintptr_t)cf + 255) & ~(uintptr_t)255;
    u16* c_W2i = (u16*)p;                        // 32768 f16 = 64 KB (interleaved)
    p = (p + 32768*2 + 255) & ~(uintptr_t)255;
    u32* h1g = (u32*)p;                          // 512*32*256 u32 = 16.78 MB (fp16-packed)
    p = (p + (size_t)BATCH*NN*256*4 + 255) & ~(uintptr_t)255;
    float* hlng = (float*)p;                     // 512*64*32 f32 = 4.19 MB
    p = (p + (size_t)BATCH*HID*NN*4 + 255) & ~(uintptr_t)255;
    u16* y1g = (u16*)p;                          // 512*64*64 f16 = 4.19 MB

    const int* ei = (const int*)d_in[1];

    CvtDesc d;
    const int srcIdx[20] = {0,2,3,4,5,7,8,9,10,11,12,13,14,15,16,17,18,19,20,21};
    void* dsts[20] = {c_x,c_W1,c_as1,c_ad1,c_b1,c_as2,c_ad2,c_b2,c_gam,c_bet,
                      c_Wi1,c_Wh1,c_bi1,c_bh1,c_Wi2,c_Wh2,c_bi2,c_bh2,c_Wf,c_bf};
    const int ns[20] = {196608,6144,512,512,512,64,64,64,64,64,
                        6144,12288,192,192,12288,12288,192,192,576,9};
    for(int i=0;i<20;i++){ d.src[i]=d_in[srcIdx[i]]; d.dst[i]=dsts[i]; d.n[i]=ns[i]; }

    k_detect <<<dim3(1),dim3(256),0,stream>>>((const u32*)d_in[0], flag);
    k_convert<<<dim3(20,8),dim3(256),0,stream>>>(d, flag);
    k_w2i    <<<dim3(128),dim3(256),0,stream>>>(d_in[6], c_W2i, flag);
    k_gat1   <<<dim3(BATCH),dim3(256),0,stream>>>(c_x,ei,c_W1,c_as1,c_ad1,c_b1,h1g);
    k_gat2ln <<<dim3(BATCH),dim3(256),0,stream>>>(h1g,ei,(const uint4*)c_W2i,c_as2,c_ad2,c_b2,c_gam,c_bet,hlng);
    k_gru1   <<<dim3(BATCH),dim3(64),0,stream>>>(hlng,c_Wi1,c_Wh1,c_bi1,c_bh1,y1g);
    k_gru2   <<<dim3(BATCH),dim3(64),0,stream>>>(y1g,c_Wi2,c_Wh2,c_bi2,c_bh2,c_Wf,c_bf,d_out,flag);
}

// Round 5
// 262.555 us; speedup vs baseline: 1.3888x; 1.0943x over previous
//
#include <hip/hip_runtime.h>
#include <hip/hip_bf16.h>
#include <stdint.h>

#define BATCH 512
#define NN 32
#define T_IN 12
#define HID 64
#define HEADS 8
#define OUT_CH 9
#define EPB (NN*8)       // 256 edges per batch (before self loops)
#define ETOT (EPB+NN)    // 288 with self loops
#define F1 (HEADS*HID)   // 512

using u16 = unsigned short;
using u32 = unsigned int;
typedef _Float16 f16;
typedef _Float16 f16x2 __attribute__((ext_vector_type(2)));

__device__ __forceinline__ float bf2f(u16 u){ return __uint_as_float(((u32)u)<<16); }
__device__ __forceinline__ u16 f2bf(float f){
    u32 x = __float_as_uint(f);
    u32 r = (x + 0x7FFFu + ((x>>16)&1u))>>16;
    return (u16)r;
}
__device__ __forceinline__ u32 packf16(float a, float b){
    f16x2 p; p.x=(f16)a; p.y=(f16)b; return __builtin_bit_cast(u32,p);
}
__device__ __forceinline__ u16 f2h16(float a){ f16 h=(f16)a; return __builtin_bit_cast(u16,h); }
__device__ __forceinline__ float lof(u32 w){ return (float)__builtin_bit_cast(f16x2,w).x; }
__device__ __forceinline__ float hif(u32 w){ return (float)__builtin_bit_cast(f16x2,w).y; }
__device__ __forceinline__ float dot2(u32 a, u32 b, float c){
#if __has_builtin(__builtin_amdgcn_fdot2)
    return __builtin_amdgcn_fdot2(__builtin_bit_cast(f16x2,a), __builtin_bit_cast(f16x2,b), c, false);
#else
    return fmaf(lof(a),lof(b), fmaf(hif(a),hif(b), c));
#endif
}
__device__ __forceinline__ float elu1(float x){ return x > 0.f ? x : (__expf(x)-1.f); }
__device__ __forceinline__ float sigm(float x){ return 1.f/(1.f+__expf(-x)); }
__device__ __forceinline__ float tanh_(float x){ return 1.f - 2.f/(__expf(2.f*x)+1.f); }

// ------------------------------------------------ dtype detection (fp32 vs bf16)
__global__ __launch_bounds__(256) void k_detect(const u32* __restrict__ xw, int* __restrict__ flag){
    __shared__ int cnt;
    if(threadIdx.x==0) cnt=0;
    __syncthreads();
    int c=0;
    for(int i=threadIdx.x;i<4096;i+=256){
        u32 w=xw[i];
        if(w & 0x7FFFFFFFu){
            u32 el=(w>>7)&0xFFu;
            if(el>=0x90u) c++;
        }
    }
    atomicAdd(&cnt,c);
    __syncthreads();
    if(threadIdx.x==0) *flag = (cnt>256) ? 1 : 0;   // 1 = fp32 inputs, 0 = bf16
}

// ------------------------------------------------ canonicalize inputs into ws (fp32)
struct CvtDesc {
    const void* src[20];
    void*       dst[20];
    int         n[20];
};

__global__ __launch_bounds__(256) void k_convert(CvtDesc d, const int* __restrict__ flag){
    const int seg = blockIdx.x;
    const int f = *flag;
    const void* s = d.src[seg];
    const int n = d.n[seg];
    const int stride = gridDim.y*256;
    float* o=(float*)d.dst[seg];
    for(int i=blockIdx.y*256+threadIdx.x;i<n;i+=stride)
        o[i] = f ? ((const float*)s)[i] : bf2f(((const u16*)s)[i]);
}

// W2 [512][64] -> interleaved fp16 W2i[(k>>3)*64+j][k&7]
__global__ __launch_bounds__(256) void k_w2i(const void* __restrict__ W2src, u16* __restrict__ W2i,
                                             const int* __restrict__ flag){
    int i = blockIdx.x*256+threadIdx.x;            // i = k*64+j
    int k=i>>6, j=i&63;
    float v = (*flag)? ((const float*)W2src)[i] : bf2f(((const u16*)W2src)[i]);
    W2i[ (((size_t)(k>>3)*64 + j)<<3) + (k&7) ] = f2h16(v);
}

// ---------------------------------------------------------------- GAT layer 1
__global__ __launch_bounds__(256,2) void k_gat1(
    const float* __restrict__ x, const int* __restrict__ ei,
    const float* __restrict__ W1, const float* __restrict__ a_s, const float* __restrict__ a_d,
    const float* __restrict__ b1, u32* __restrict__ h1g)
{
    const int b = blockIdx.x, t = threadIdx.x;
    __shared__ __align__(16) float s_x[NN][12];
    __shared__ float s_W1[T_IN*F1];
    __shared__ __align__(16) u16 s_h[NN][520];     // fp16, row pad 8 (16B-aligned rows)
    __shared__ u32 s_aspk[HEADS*32], s_adpk[HEADS*32];
    __shared__ float s_es[NN][HEADS], s_ed[NN][HEADS];
    __shared__ unsigned char s_src[ETOT], s_dst[ETOT];
    __shared__ float s_al[ETOT][HEADS];
    __shared__ int s_cnt[NN], s_off[NN], s_fil[NN];
    __shared__ short s_lst[ETOT];

    for(int i=t;i<NN*T_IN;i+=256) s_x[i/12][i%12] = x[b*NN*T_IN + i];
    for(int i=t;i<T_IN*F1;i+=256) s_W1[i]=W1[i];
    s_aspk[t]=packf16(a_s[2*t],a_s[2*t+1]);
    s_adpk[t]=packf16(a_d[2*t],a_d[2*t+1]);
    if(t<EPB){
        s_src[t] = (unsigned char)(ei[b*EPB+t] - b*NN);
        s_dst[t] = (unsigned char)(ei[(size_t)BATCH*EPB + b*EPB+t] - b*NN);
    }
    if(t<NN){ s_src[EPB+t]=s_dst[EPB+t]=(unsigned char)t; s_cnt[t]=0; s_fil[t]=0; }
    __syncthreads();

    // h = x @ W1 (pre-bias) -> LDS fp16 ; thread t owns columns t and t+256
    {
        float w0[12], w1[12];
        #pragma unroll
        for(int k=0;k<12;k++){ w0[k]=s_W1[k*F1+t]; w1[k]=s_W1[k*F1+t+256]; }
        for(int n=0;n<NN;n++){
            float xr[12];
            const float4* xp=(const float4*)s_x[n];
            *(float4*)&xr[0]=xp[0]; *(float4*)&xr[4]=xp[1]; *(float4*)&xr[8]=xp[2];
            float A=0.f,B=0.f;
            #pragma unroll
            for(int k=0;k<12;k++){ A=fmaf(xr[k],w0[k],A); B=fmaf(xr[k],w1[k],B); }
            s_h[n][t]=f2h16(A); s_h[n][t+256]=f2h16(B);
        }
    }
    for(int e=t;e<ETOT;e+=256) atomicAdd(&s_cnt[s_dst[e]],1);
    __syncthreads();

    // es/ed per (node, head) via fp16 dot2
    {
        int n=t&31, hd=t>>5;
        const uint4* hp=(const uint4*)((const u16*)s_h[n] + hd*64);
        u32 hw[32];
        #pragma unroll
        for(int q=0;q<8;q++) *(uint4*)&hw[q*4]=hp[q];
        float e1=0.f,e2=0.f;
        #pragma unroll
        for(int k=0;k<32;k++){ e1=dot2(hw[k],s_aspk[hd*32+k],e1); e2=dot2(hw[k],s_adpk[hd*32+k],e2); }
        s_es[n][hd]=e1; s_ed[n][hd]=e2;
    }
    if(t==0){ int o=0; for(int i=0;i<NN;i++){ s_off[i]=o; o+=s_cnt[i]; } }
    __syncthreads();

    for(int e=t;e<ETOT;e+=256){
        int d=s_dst[e]; int p=atomicAdd(&s_fil[d],1); s_lst[s_off[d]+p]=(short)e;
    }
    for(int e=t;e<ETOT;e+=256){
        int s=s_src[e], d=s_dst[e];
        #pragma unroll
        for(int hd=0;hd<HEADS;hd++){
            float v = s_es[s][hd]+s_ed[d][hd];
            s_al[e][hd] = v>0.f? v : 0.2f*v;
        }
    }
    __syncthreads();

    // per-(dst,head) softmax
    {
        int d=t>>3, hd=t&7;
        int o=s_off[d], c=s_cnt[d];
        float m=-1e30f;
        for(int i=0;i<c;i++) m = fmaxf(m, s_al[s_lst[o+i]][hd]);
        float ss=0.f;
        for(int i=0;i<c;i++){ int e=s_lst[o+i]; float p=__expf(s_al[e][hd]-m); s_al[e][hd]=p; ss+=p; }
        float inv = 1.f/(ss+1e-16f);
        for(int i=0;i<c;i++) s_al[s_lst[o+i]][hd]*=inv;
    }
    __syncthreads();

    // aggregate in 4 column-chunks of 16, +b1, ELU, store fp16-packed
    {
        int d=t&31, hd=t>>5;
        int o=s_off[d], cnt=s_cnt[d];
        size_t obase = ((size_t)(b*NN+d))*256 + hd*32;
        #pragma unroll
        for(int ch=0;ch<4;ch++){
            float acc[16];
            #pragma unroll
            for(int i=0;i<16;i++) acc[i]=0.f;
            for(int i=0;i<cnt;i++){
                int e=s_lst[o+i]; float a=s_al[e][hd]; int sr=s_src[e];
                const uint4* hp=(const uint4*)((const u16*)s_h[sr] + hd*64 + ch*16);
                u32 pw[8];
                *(uint4*)&pw[0]=hp[0]; *(uint4*)&pw[4]=hp[1];
                #pragma unroll
                for(int q=0;q<8;q++){ acc[2*q]+=a*lof(pw[q]); acc[2*q+1]+=a*hif(pw[q]); }
            }
            u32* op = h1g + obase + ch*8;
            #pragma unroll
            for(int j=0;j<8;j++){
                float v0=elu1(acc[2*j]   + b1[hd*64+ch*16+2*j]);
                float v1=elu1(acc[2*j+1] + b1[hd*64+ch*16+2*j+1]);
                op[j]=packf16(v0,v1);
            }
        }
    }
}

// --------------------------------------------- GAT layer 2 + LayerNorm (+transpose)
__global__ __launch_bounds__(256,2) void k_gat2ln(
    const u32* __restrict__ h1g, const int* __restrict__ ei,
    const uint4* __restrict__ W2i, const float* __restrict__ a_s2, const float* __restrict__ a_d2,
    const float* __restrict__ b2, const float* __restrict__ gam, const float* __restrict__ bet,
    float* __restrict__ hlng)
{
    const int b=blockIdx.x, t=threadIdx.x;
    __shared__ __align__(16) u32 s_h1[NN*260];   // fp16-packed rows, padded to 260 u32
    __shared__ float s_h2[NN][HID];
    __shared__ float s_es[NN], s_ed[NN];
    __shared__ unsigned char s_src[ETOT], s_dst[ETOT];
    __shared__ float s_al[ETOT];
    __shared__ int s_cnt[NN], s_off[NN], s_fil[NN];
    __shared__ short s_lst[ETOT];

    { const u32* g = h1g + (size_t)b*8192;
      for(int w=t; w<8192; w+=256){ int n=w>>8, c=w&255; s_h1[n*260+c]=g[w]; } }
    if(t<EPB){
        s_src[t]=(unsigned char)(ei[b*EPB+t]-b*NN);
        s_dst[t]=(unsigned char)(ei[(size_t)BATCH*EPB+b*EPB+t]-b*NN);
    }
    if(t<NN){ s_src[EPB+t]=s_dst[EPB+t]=(unsigned char)t; s_cnt[t]=0; s_fil[t]=0; }
    __syncthreads();

    for(int e=t;e<ETOT;e+=256) atomicAdd(&s_cnt[s_dst[e]],1);
    // GEMM h2 = h1 @ W2 : 2 rows x 4 cols per thread, fp16 dot2, W2 interleaved from global
    {
        int n0=(t>>4)<<1, j0=(t&15)<<2;
        const u32* r0=&s_h1[n0*260];
        const u32* r1=&s_h1[(n0+1)*260];
        float a00=0,a01=0,a02=0,a03=0,a10=0,a11=0,a12=0,a13=0;
        for(int kb=0;kb<64;kb++){
            uint4 A0=*(const uint4*)&r0[kb*4];
            uint4 A1=*(const uint4*)&r1[kb*4];
            const uint4* wp=&W2i[kb*64+j0];
            uint4 w0=wp[0], w1=wp[1], w2=wp[2], w3=wp[3];
            a00=dot2(A0.x,w0.x,a00); a00=dot2(A0.y,w0.y,a00); a00=dot2(A0.z,w0.z,a00); a00=dot2(A0.w,w0.w,a00);
            a01=dot2(A0.x,w1.x,a01); a01=dot2(A0.y,w1.y,a01); a01=dot2(A0.z,w1.z,a01); a01=dot2(A0.w,w1.w,a01);
            a02=dot2(A0.x,w2.x,a02); a02=dot2(A0.y,w2.y,a02); a02=dot2(A0.z,w2.z,a02); a02=dot2(A0.w,w2.w,a02);
            a03=dot2(A0.x,w3.x,a03); a03=dot2(A0.y,w3.y,a03); a03=dot2(A0.z,w3.z,a03); a03=dot2(A0.w,w3.w,a03);
            a10=dot2(A1.x,w0.x,a10); a10=dot2(A1.y,w0.y,a10); a10=dot2(A1.z,w0.z,a10); a10=dot2(A1.w,w0.w,a10);
            a11=dot2(A1.x,w1.x,a11); a11=dot2(A1.y,w1.y,a11); a11=dot2(A1.z,w1.z,a11); a11=dot2(A1.w,w1.w,a11);
            a12=dot2(A1.x,w2.x,a12); a12=dot2(A1.y,w2.y,a12); a12=dot2(A1.z,w2.z,a12); a12=dot2(A1.w,w2.w,a12);
            a13=dot2(A1.x,w3.x,a13); a13=dot2(A1.y,w3.y,a13); a13=dot2(A1.z,w3.z,a13); a13=dot2(A1.w,w3.w,a13);
        }
        s_h2[n0][j0]=a00; s_h2[n0][j0+1]=a01; s_h2[n0][j0+2]=a02; s_h2[n0][j0+3]=a03;
        s_h2[n0+1][j0]=a10; s_h2[n0+1][j0+1]=a11; s_h2[n0+1][j0+2]=a12; s_h2[n0+1][j0+3]=a13;
    }
    __syncthreads();

    // es/ed (single head) via 8-lane shuffle reduce
    {
        int n=t>>3, g=t&7;
        float e1=0,e2=0;
        #pragma unroll
        for(int cc=0; cc<8; cc++){
            float hv = s_h2[n][g*8+cc];
            e1 += hv*a_s2[g*8+cc];
            e2 += hv*a_d2[g*8+cc];
        }
        #pragma unroll
        for(int m=1;m<8;m<<=1){ e1 += __shfl_xor(e1,m,64); e2 += __shfl_xor(e2,m,64); }
        if(g==0){ s_es[n]=e1; s_ed[n]=e2; }
    }
    if(t==0){ int o=0; for(int i=0;i<NN;i++){ s_off[i]=o; o+=s_cnt[i]; } }
    __syncthreads();

    for(int e=t;e<ETOT;e+=256){
        int d=s_dst[e]; int p=atomicAdd(&s_fil[d],1); s_lst[s_off[d]+p]=(short)e;
    }
    for(int e=t;e<ETOT;e+=256){
        float v = s_es[s_src[e]] + s_ed[s_dst[e]];
        s_al[e] = v>0.f? v:0.2f*v;
    }
    __syncthreads();

    if(t<NN){
        int o=s_off[t], c=s_cnt[t];
        float m=-1e30f;
        for(int i=0;i<c;i++) m=fmaxf(m, s_al[s_lst[o+i]]);
        float ss=0;
        for(int i=0;i<c;i++){int e=s_lst[o+i]; float p=__expf(s_al[e]-m); s_al[e]=p; ss+=p;}
        float inv=1.f/(ss+1e-16f);
        for(int i=0;i<c;i++) s_al[s_lst[o+i]]*=inv;
    }
    __syncthreads();

    // aggregate + b2 + ELU + LayerNorm + transposed store [b][c][n]
    {
        int n=t>>3, g=t&7;
        float acc[8];
        #pragma unroll
        for(int i=0;i<8;i++) acc[i]=0;
        int o=s_off[n], cnt=s_cnt[n];
        for(int i=0;i<cnt;i++){
            int e=s_lst[o+i]; float a=s_al[e]; int sr=s_src[e];
            const float4* hp=(const float4*)&s_h2[sr][g*8];
            float4 v0=hp[0], v1=hp[1];
            acc[0]+=a*v0.x; acc[1]+=a*v0.y; acc[2]+=a*v0.z; acc[3]+=a*v0.w;
            acc[4]+=a*v1.x; acc[5]+=a*v1.y; acc[6]+=a*v1.z; acc[7]+=a*v1.w;
        }
        float sum=0,sq=0;
        #pragma unroll
        for(int i=0;i<8;i++){
            float v = elu1(acc[i] + b2[g*8+i]);
            acc[i]=v; sum+=v; sq+=v*v;
        }
        #pragma unroll
        for(int m=1;m<8;m<<=1){ sum+=__shfl_xor(sum,m,64); sq+=__shfl_xor(sq,m,64); }
        float mu = sum*(1.f/64.f);
        float var = sq*(1.f/64.f) - mu*mu;
        float rs = rsqrtf(var + 1e-5f);
        float* outp = hlng + (size_t)b*HID*NN;
        #pragma unroll
        for(int i=0;i<8;i++){
            int c=g*8+i;
            float v=(acc[i]-mu)*rs*gam[c] + bet[c];
            outp[c*NN + n] = v;
        }
    }
}

// --------------------------------- Fused GRU1+GRU2+FC, pipelined, k-split by 2
// 256 threads = 4 waves. waves 0-1: GRU1 (k-halves 0/1); waves 2-3: GRU2.
// Iteration it: GRU1 computes step it (it<64); GRU2 computes step it-1 (it>=1).
__global__ __launch_bounds__(256,2) void k_gruf(
    const float* __restrict__ hlng,
    const float* __restrict__ Wi1, const float* __restrict__ Wh1,
    const float* __restrict__ bi1, const float* __restrict__ bh1,
    const float* __restrict__ Wi2, const float* __restrict__ Wh2,
    const float* __restrict__ bi2, const float* __restrict__ bh2,
    const float* __restrict__ Wf, const float* __restrict__ bfv,
    void* __restrict__ outp, const int* __restrict__ flag)
{
    const int b=blockIdx.x, t=threadIdx.x;
    const int wave=t>>6, lane=t&63;
    const int layer=wave>>1;      // 0 = GRU1, 1 = GRU2
    const int s=wave&1;           // k-half
    const int u=lane;             // hidden unit

    __shared__ __align__(16) u32 s_x1[64*16];  // GRU1 input fp16-packed [step][16]
    __shared__ __align__(16) u32 s_y[2][32];   // y1 double buffer (64 f16)
    __shared__ __align__(16) u32 s_h1w[32];    // h1 fp16-packed
    __shared__ __align__(16) u32 s_h2w[32];    // h2 fp16-packed
    __shared__ float s_p1[4*64];               // half-1 partials GRU1 (r,z,xn,hn)
    __shared__ float s_p2[4*64];               // half-1 partials GRU2
    __shared__ float s_h2f[64];                // final h2 fp32

    { const float2* g=(const float2*)(hlng + (size_t)b*2048);
      for(int w=t;w<1024;w+=256){ float2 v=g[w]; s_x1[w]=packf16(v.x,v.y); } }
    if(t<32){ s_h1w[t]=0u; s_h2w[t]=0u; }

    // ---- per-thread packed weights (half rows) ----
    u32 wiR[16],wiZ[16],wiN[16],whR[16],whZ[16],whN[16];
    if(layer==0){
        const float2* WiF=(const float2*)Wi1;   // rows of 16 float2
        const float2* WhF=(const float2*)Wh1;   // rows of 32 float2
        #pragma unroll
        for(int k=0;k<8;k++){
            float2 a=WiF[u*16+s*8+k], c=WiF[(64+u)*16+s*8+k], d=WiF[(128+u)*16+s*8+k];
            wiR[k]=packf16(a.x,a.y); wiZ[k]=packf16(c.x,c.y); wiN[k]=packf16(d.x,d.y);
        }
        #pragma unroll
        for(int k=0;k<16;k++){
            float2 a=WhF[u*32+s*16+k], c=WhF[(64+u)*32+s*16+k], d=WhF[(128+u)*32+s*16+k];
            whR[k]=packf16(a.x,a.y); whZ[k]=packf16(c.x,c.y); whN[k]=packf16(d.x,d.y);
        }
    } else {
        const float2* WiF=(const float2*)Wi2;   // rows of 32 float2
        const float2* WhF=(const float2*)Wh2;
        #pragma unroll
        for(int k=0;k<16;k++){
            float2 a=WiF[u*32+s*16+k], c=WiF[(64+u)*32+s*16+k], d=WiF[(128+u)*32+s*16+k];
            wiR[k]=packf16(a.x,a.y); wiZ[k]=packf16(c.x,c.y); wiN[k]=packf16(d.x,d.y);
            float2 e=WhF[u*32+s*16+k], f=WhF[(64+u)*32+s*16+k], g2=WhF[(128+u)*32+s*16+k];
            whR[k]=packf16(e.x,e.y); whZ[k]=packf16(f.x,f.y); whN[k]=packf16(g2.x,g2.y);
        }
    }
    float br=0.f,bz=0.f,bxn=0.f,bhn=0.f,h=0.f;
    if(s==0){
        const float* bi = layer? bi2:bi1;
        const float* bh = layer? bh2:bh1;
        br=bi[u]+bh[u]; bz=bi[64+u]+bh[64+u]; bxn=bi[128+u]; bhn=bh[128+u];
    }
    float* sp = layer? s_p2 : s_p1;
    __syncthreads();

    for(int it=0; it<=64; ++it){
        float pr=0.f,pz=0.f,pxn=0.f,phn=0.f;
        bool act;
        if(layer==0){
            act = (it<64);
            if(act){
                u32 xw[8], hw[16];
                const uint4* xp=(const uint4*)&s_x1[it*16+s*8];
                *(uint4*)&xw[0]=xp[0]; *(uint4*)&xw[4]=xp[1];
                const uint4* hp=(const uint4*)&s_h1w[s*16];
                #pragma unroll
                for(int q=0;q<4;q++) *(uint4*)&hw[q*4]=hp[q];
                #pragma unroll
                for(int k=0;k<8;k++){ pr=dot2(xw[k],wiR[k],pr); pz=dot2(xw[k],wiZ[k],pz); pxn=dot2(xw[k],wiN[k],pxn); }
                #pragma unroll
                for(int k=0;k<16;k++){ pr=dot2(hw[k],whR[k],pr); pz=dot2(hw[k],whZ[k],pz); phn=dot2(hw[k],whN[k],phn); }
            }
        } else {
            act = (it>=1);
            if(act){
                u32 xw[16], hw[16];
                const uint4* xp=(const uint4*)&s_y[(it-1)&1][s*16];
                #pragma unroll
                for(int q=0;q<4;q++) *(uint4*)&xw[q*4]=xp[q];
                const uint4* hp=(const uint4*)&s_h2w[s*16];
                #pragma unroll
                for(int q=0;q<4;q++) *(uint4*)&hw[q*4]=hp[q];
                #pragma unroll
                for(int k=0;k<16;k++){
                    pr=dot2(xw[k],wiR[k],pr); pz=dot2(xw[k],wiZ[k],pz); pxn=dot2(xw[k],wiN[k],pxn);
                    pr=dot2(hw[k],whR[k],pr); pz=dot2(hw[k],whZ[k],pz); phn=dot2(hw[k],whN[k],phn);
                }
            }
        }
        if(act && s==1){ sp[u]=pr; sp[64+u]=pz; sp[128+u]=pxn; sp[192+u]=phn; }
        __syncthreads();
        if(act && s==0){
            float ar = pr + sp[u] + br;
            float az = pz + sp[64+u] + bz;
            float axn = pxn + sp[128+u] + bxn;
            float ahn = phn + sp[192+u] + bhn;
            float r=sigm(ar), z=sigm(az);
            float n=tanh_(axn + r*ahn);
            h=(1.f-z)*n + z*h;
            u16 hp16=f2h16(h);
            if(layer==0){
                ((u16*)s_h1w)[u]=hp16;
                ((u16*)s_y[it&1])[u]=hp16;
            } else {
                ((u16*)s_h2w)[u]=hp16;
                if(it==64) s_h2f[u]=h;
            }
        }
        __syncthreads();
    }

    if(t<OUT_CH){
        float acc=bfv[t];
        #pragma unroll
        for(int i=0;i<64;i++) acc += s_h2f[i]*Wf[t*64+i];
        if(*flag) ((float*)outp)[b*OUT_CH+t]=acc;
        else      ((u16*)outp)[b*OUT_CH+t]=f2bf(acc);
    }
}

extern "C" void kernel_launch(void* const* d_in, const int* in_sizes, int n_in,
                              void* d_out, int out_size, void* d_ws, size_t ws_size,
                              hipStream_t stream)
{
    char* ws=(char*)d_ws;
    int* flag = (int*)ws;
    float* cf = (float*)(ws + 256);
    float* c_x   = cf; cf+=196608;
    float* c_W1  = cf; cf+=6144;
    float* c_as1 = cf; cf+=512;
    float* c_ad1 = cf; cf+=512;
    float* c_b1  = cf; cf+=512;
    float* c_as2 = cf; cf+=64;
    float* c_ad2 = cf; cf+=64;
    float* c_b2  = cf; cf+=64;
    float* c_gam = cf; cf+=64;
    float* c_bet = cf; cf+=64;
    float* c_Wi1 = cf; cf+=6144;
    float* c_Wh1 = cf; cf+=12288;
    float* c_bi1 = cf; cf+=192;
    float* c_bh1 = cf; cf+=192;
    float* c_Wi2 = cf; cf+=12288;
    float* c_Wh2 = cf; cf+=12288;
    float* c_bi2 = cf; cf+=192;
    float* c_bh2 = cf; cf+=192;
    float* c_Wf  = cf; cf+=576;
    float* c_bf  = cf; cf+=9;
    uintptr_t p = ((uintptr_t)cf + 255) & ~(uintptr_t)255;
    u16* c_W2i = (u16*)p;                        // 32768 f16 = 64 KB (interleaved)
    p = (p + 32768*2 + 255) & ~(uintptr_t)255;
    u32* h1g = (u32*)p;                          // 512*32*256 u32 = 16.78 MB (fp16-packed)
    p = (p + (size_t)BATCH*NN*256*4 + 255) & ~(uintptr_t)255;
    float* hlng = (float*)p;                     // 512*64*32 f32 = 4.19 MB

    const int* ei = (const int*)d_in[1];

    CvtDesc d;
    const int srcIdx[20] = {0,2,3,4,5,7,8,9,10,11,12,13,14,15,16,17,18,19,20,21};
    void* dsts[20] = {c_x,c_W1,c_as1,c_ad1,c_b1,c_as2,c_ad2,c_b2,c_gam,c_bet,
                      c_Wi1,c_Wh1,c_bi1,c_bh1,c_Wi2,c_Wh2,c_bi2,c_bh2,c_Wf,c_bf};
    const int ns[20] = {196608,6144,512,512,512,64,64,64,64,64,
                        6144,12288,192,192,12288,12288,192,192,576,9};
    for(int i=0;i<20;i++){ d.src[i]=d_in[srcIdx[i]]; d.dst[i]=dsts[i]; d.n[i]=ns[i]; }

    k_detect <<<dim3(1),dim3(256),0,stream>>>((const u32*)d_in[0], flag);
    k_convert<<<dim3(20,8),dim3(256),0,stream>>>(d, flag);
    k_w2i    <<<dim3(128),dim3(256),0,stream>>>(d_in[6], c_W2i, flag);
    k_gat1   <<<dim3(BATCH),dim3(256),0,stream>>>(c_x,ei,c_W1,c_as1,c_ad1,c_b1,h1g);
    k_gat2ln <<<dim3(BATCH),dim3(256),0,stream>>>(h1g,ei,(const uint4*)c_W2i,c_as2,c_ad2,c_b2,c_gam,c_bet,hlng);
    k_gruf   <<<dim3(BATCH),dim3(256),0,stream>>>(hlng,c_Wi1,c_Wh1,c_bi1,c_bh1,
                                                  c_Wi2,c_Wh2,c_bi2,c_bh2,c_Wf,c_bf,d_out,flag);
}

// Round 6
// 259.964 us; speedup vs baseline: 1.4027x; 1.0100x over previous
//
#include <hip/hip_runtime.h>
#include <hip/hip_bf16.h>
#include <stdint.h>

#define BATCH 512
#define NN 32
#define T_IN 12
#define HID 64
#define HEADS 8
#define OUT_CH 9
#define EPB (NN*8)       // 256 edges per batch (before self loops)
#define ETOT (EPB+NN)    // 288 with self loops
#define F1 (HEADS*HID)   // 512

using u16 = unsigned short;
using u32 = unsigned int;
typedef _Float16 f16;
typedef _Float16 f16x2 __attribute__((ext_vector_type(2)));

__device__ __forceinline__ float bf2f(u16 u){ return __uint_as_float(((u32)u)<<16); }
__device__ __forceinline__ u16 f2bf(float f){
    u32 x = __float_as_uint(f);
    u32 r = (x + 0x7FFFu + ((x>>16)&1u))>>16;
    return (u16)r;
}
__device__ __forceinline__ u32 packf16(float a, float b){
    f16x2 p; p.x=(f16)a; p.y=(f16)b; return __builtin_bit_cast(u32,p);
}
__device__ __forceinline__ u16 f2h16(float a){ f16 h=(f16)a; return __builtin_bit_cast(u16,h); }
__device__ __forceinline__ float lof(u32 w){ return (float)__builtin_bit_cast(f16x2,w).x; }
__device__ __forceinline__ float hif(u32 w){ return (float)__builtin_bit_cast(f16x2,w).y; }
__device__ __forceinline__ float dot2(u32 a, u32 b, float c){
#if __has_builtin(__builtin_amdgcn_fdot2)
    return __builtin_amdgcn_fdot2(__builtin_bit_cast(f16x2,a), __builtin_bit_cast(f16x2,b), c, false);
#else
    return fmaf(lof(a),lof(b), fmaf(hif(a),hif(b), c));
#endif
}
__device__ __forceinline__ float elu1(float x){ return x > 0.f ? x : (__expf(x)-1.f); }
__device__ __forceinline__ float sigm(float x){ return 1.f/(1.f+__expf(-x)); }
__device__ __forceinline__ float tanh_(float x){ return 1.f - 2.f/(__expf(2.f*x)+1.f); }
// order-preserving float->u32 key for atomicMax
__device__ __forceinline__ u32 fenc(float v){
    u32 b=__float_as_uint(v);
    return (b&0x80000000u) ? ~b : (b|0x80000000u);
}
__device__ __forceinline__ float fdec(u32 k){
    return __uint_as_float((k&0x80000000u) ? (k&0x7FFFFFFFu) : ~k);
}

// ------------------------------------------------ dtype detection (fp32 vs bf16)
__global__ __launch_bounds__(256) void k_detect(const u32* __restrict__ xw, int* __restrict__ flag){
    __shared__ int cnt;
    if(threadIdx.x==0) cnt=0;
    __syncthreads();
    int c=0;
    for(int i=threadIdx.x;i<4096;i+=256){
        u32 w=xw[i];
        if(w & 0x7FFFFFFFu){
            u32 el=(w>>7)&0xFFu;
            if(el>=0x90u) c++;
        }
    }
    atomicAdd(&cnt,c);
    __syncthreads();
    if(threadIdx.x==0) *flag = (cnt>256) ? 1 : 0;   // 1 = fp32 inputs, 0 = bf16
}

// ------------------------------------------------ canonicalize inputs into ws (fp32)
struct CvtDesc {
    const void* src[20];
    void*       dst[20];
    int         n[20];
};

__global__ __launch_bounds__(256) void k_convert(CvtDesc d, const int* __restrict__ flag){
    const int seg = blockIdx.x;
    const int f = *flag;
    const void* s = d.src[seg];
    const int n = d.n[seg];
    const int stride = gridDim.y*256;
    float* o=(float*)d.dst[seg];
    for(int i=blockIdx.y*256+threadIdx.x;i<n;i+=stride)
        o[i] = f ? ((const float*)s)[i] : bf2f(((const u16*)s)[i]);
}

// W2 [512][64] -> interleaved fp16 W2i[(k>>3)*64+j][k&7]
__global__ __launch_bounds__(256) void k_w2i(const void* __restrict__ W2src, u16* __restrict__ W2i,
                                             const int* __restrict__ flag){
    int i = blockIdx.x*256+threadIdx.x;            // i = k*64+j
    int k=i>>6, j=i&63;
    float v = (*flag)? ((const float*)W2src)[i] : bf2f(((const u16*)W2src)[i]);
    W2i[ (((size_t)(k>>3)*64 + j)<<3) + (k&7) ] = f2h16(v);
}

// ---------------------------------------------------------------- GAT layer 1
__global__ __launch_bounds__(256,2) void k_gat1(
    const float* __restrict__ x, const int* __restrict__ ei,
    const float* __restrict__ W1, const float* __restrict__ a_s, const float* __restrict__ a_d,
    const float* __restrict__ b1, u32* __restrict__ h1g)
{
    const int b = blockIdx.x, t = threadIdx.x;
    __shared__ __align__(16) float s_x[NN][12];
    __shared__ float s_W1[T_IN*F1];
    __shared__ __align__(16) u16 s_h[NN][520];     // fp16, row pad 8 (16B-aligned rows)
    __shared__ u32 s_aspk[HEADS*32], s_adpk[HEADS*32];
    __shared__ float s_es[NN][HEADS], s_ed[NN][HEADS];
    __shared__ unsigned char s_src[ETOT], s_dst[ETOT];
    __shared__ float s_al[ETOT][HEADS];
    __shared__ u32 s_mx[NN*HEADS];
    __shared__ float s_sm[NN*HEADS], s_inv[NN*HEADS];
    __shared__ int s_cnt[NN], s_off[NN], s_fil[NN];
    __shared__ short s_lst[ETOT];

    for(int i=t;i<NN*T_IN;i+=256) s_x[i/12][i%12] = x[b*NN*T_IN + i];
    for(int i=t;i<T_IN*F1;i+=256) s_W1[i]=W1[i];
    s_aspk[t]=packf16(a_s[2*t],a_s[2*t+1]);
    s_adpk[t]=packf16(a_d[2*t],a_d[2*t+1]);
    s_mx[t]=0u; s_sm[t]=0.f;
    if(t<EPB){
        s_src[t] = (unsigned char)(ei[b*EPB+t] - b*NN);
        s_dst[t] = (unsigned char)(ei[(size_t)BATCH*EPB + b*EPB+t] - b*NN);
    }
    if(t<NN){ s_src[EPB+t]=s_dst[EPB+t]=(unsigned char)t; s_cnt[t]=0; s_fil[t]=0; }
    __syncthreads();

    // h = x @ W1 (pre-bias) -> LDS fp16 ; thread t owns columns t and t+256
    {
        float w0[12], w1[12];
        #pragma unroll
        for(int k=0;k<12;k++){ w0[k]=s_W1[k*F1+t]; w1[k]=s_W1[k*F1+t+256]; }
        for(int n=0;n<NN;n++){
            float xr[12];
            const float4* xp=(const float4*)s_x[n];
            *(float4*)&xr[0]=xp[0]; *(float4*)&xr[4]=xp[1]; *(float4*)&xr[8]=xp[2];
            float A=0.f,B=0.f;
            #pragma unroll
            for(int k=0;k<12;k++){ A=fmaf(xr[k],w0[k],A); B=fmaf(xr[k],w1[k],B); }
            s_h[n][t]=f2h16(A); s_h[n][t+256]=f2h16(B);
        }
    }
    for(int e=t;e<ETOT;e+=256) atomicAdd(&s_cnt[s_dst[e]],1);
    __syncthreads();

    // es/ed per (node, head) via fp16 dot2
    {
        int n=t&31, hd=t>>5;
        const uint4* hp=(const uint4*)((const u16*)s_h[n] + hd*64);
        u32 hw[32];
        #pragma unroll
        for(int q=0;q<8;q++) *(uint4*)&hw[q*4]=hp[q];
        float e1=0.f,e2=0.f;
        #pragma unroll
        for(int k=0;k<32;k++){ e1=dot2(hw[k],s_aspk[hd*32+k],e1); e2=dot2(hw[k],s_adpk[hd*32+k],e2); }
        s_es[n][hd]=e1; s_ed[n][hd]=e2;
    }
    if(t==0){ int o=0; for(int i=0;i<NN;i++){ s_off[i]=o; o+=s_cnt[i]; } }
    __syncthreads();

    // CSR fill (parallel) + edge-parallel logits + atomicMax
    for(int e=t;e<ETOT;e+=256){
        int d=s_dst[e]; int p=atomicAdd(&s_fil[d],1); s_lst[s_off[d]+p]=(short)e;
    }
    for(int i=t;i<ETOT*HEADS;i+=256){
        int e=i>>3, hd=i&7;
        int sr=s_src[e], d=s_dst[e];
        float v = s_es[sr][hd]+s_ed[d][hd];
        v = v>0.f? v : 0.2f*v;
        s_al[e][hd]=v;
        atomicMax(&s_mx[d*8+hd], fenc(v));
    }
    __syncthreads();

    // edge-parallel exp + sum
    for(int i=t;i<ETOT*HEADS;i+=256){
        int e=i>>3, hd=i&7;
        int d=s_dst[e];
        float p=__expf(s_al[e][hd]-fdec(s_mx[d*8+hd]));
        s_al[e][hd]=p;
        atomicAdd(&s_sm[d*8+hd], p);
    }
    __syncthreads();
    s_inv[t]=1.f/(s_sm[t]+1e-16f);
    __syncthreads();

    // aggregate (unscaled p), then scale by inv in epilogue; 2 column-chunks of 32
    {
        int d=t&31, hd=t>>5;
        int o=s_off[d], cnt=s_cnt[d];
        float inv=s_inv[d*8+hd];
        size_t obase = ((size_t)(b*NN+d))*256 + hd*32;
        #pragma unroll
        for(int ch=0;ch<2;ch++){
            float acc[32];
            #pragma unroll
            for(int i=0;i<32;i++) acc[i]=0.f;
            for(int i=0;i<cnt;i++){
                int e=s_lst[o+i]; float a=s_al[e][hd]; int sr=s_src[e];
                const uint4* hp=(const uint4*)((const u16*)s_h[sr] + hd*64 + ch*32);
                u32 pw[16];
                *(uint4*)&pw[0]=hp[0]; *(uint4*)&pw[4]=hp[1];
                *(uint4*)&pw[8]=hp[2]; *(uint4*)&pw[12]=hp[3];
                #pragma unroll
                for(int q=0;q<16;q++){ acc[2*q]+=a*lof(pw[q]); acc[2*q+1]+=a*hif(pw[q]); }
            }
            u32* op = h1g + obase + ch*16;
            #pragma unroll
            for(int j=0;j<16;j++){
                float v0=elu1(acc[2*j]*inv   + b1[hd*64+ch*32+2*j]);
                float v1=elu1(acc[2*j+1]*inv + b1[hd*64+ch*32+2*j+1]);
                op[j]=packf16(v0,v1);
            }
        }
    }
}

// --------------------------------------------- GAT layer 2 + LayerNorm (+transpose)
__global__ __launch_bounds__(256,2) void k_gat2ln(
    const u32* __restrict__ h1g, const int* __restrict__ ei,
    const uint4* __restrict__ W2i, const float* __restrict__ a_s2, const float* __restrict__ a_d2,
    const float* __restrict__ b2, const float* __restrict__ gam, const float* __restrict__ bet,
    float* __restrict__ hlng)
{
    const int b=blockIdx.x, t=threadIdx.x;
    __shared__ __align__(16) u32 s_h1[NN*260];   // fp16-packed rows, padded to 260 u32
    __shared__ float s_h2[NN][HID];
    __shared__ float s_es[NN], s_ed[NN];
    __shared__ unsigned char s_src[ETOT], s_dst[ETOT];
    __shared__ float s_al[ETOT];
    __shared__ u32 s_mx[NN];
    __shared__ float s_sm[NN], s_inv[NN];
    __shared__ int s_cnt[NN], s_off[NN], s_fil[NN];
    __shared__ short s_lst[ETOT];

    { const u32* g = h1g + (size_t)b*8192;
      for(int w=t; w<8192; w+=256){ int n=w>>8, c=w&255; s_h1[n*260+c]=g[w]; } }
    if(t<EPB){
        s_src[t]=(unsigned char)(ei[b*EPB+t]-b*NN);
        s_dst[t]=(unsigned char)(ei[(size_t)BATCH*EPB+b*EPB+t]-b*NN);
    }
    if(t<NN){ s_src[EPB+t]=s_dst[EPB+t]=(unsigned char)t;
              s_cnt[t]=0; s_fil[t]=0; s_mx[t]=0u; s_sm[t]=0.f; }
    __syncthreads();

    for(int e=t;e<ETOT;e+=256) atomicAdd(&s_cnt[s_dst[e]],1);
    // GEMM h2 = h1 @ W2 : 2 rows x 4 cols per thread, fp16 dot2, W2 interleaved from global
    {
        int n0=(t>>4)<<1, j0=(t&15)<<2;
        const u32* r0=&s_h1[n0*260];
        const u32* r1=&s_h1[(n0+1)*260];
        float a00=0,a01=0,a02=0,a03=0,a10=0,a11=0,a12=0,a13=0;
        for(int kb=0;kb<64;kb++){
            uint4 A0=*(const uint4*)&r0[kb*4];
            uint4 A1=*(const uint4*)&r1[kb*4];
            const uint4* wp=&W2i[kb*64+j0];
            uint4 w0=wp[0], w1=wp[1], w2=wp[2], w3=wp[3];
            a00=dot2(A0.x,w0.x,a00); a00=dot2(A0.y,w0.y,a00); a00=dot2(A0.z,w0.z,a00); a00=dot2(A0.w,w0.w,a00);
            a01=dot2(A0.x,w1.x,a01); a01=dot2(A0.y,w1.y,a01); a01=dot2(A0.z,w1.z,a01); a01=dot2(A0.w,w1.w,a01);
            a02=dot2(A0.x,w2.x,a02); a02=dot2(A0.y,w2.y,a02); a02=dot2(A0.z,w2.z,a02); a02=dot2(A0.w,w2.w,a02);
            a03=dot2(A0.x,w3.x,a03); a03=dot2(A0.y,w3.y,a03); a03=dot2(A0.z,w3.z,a03); a03=dot2(A0.w,w3.w,a03);
            a10=dot2(A1.x,w0.x,a10); a10=dot2(A1.y,w0.y,a10); a10=dot2(A1.z,w0.z,a10); a10=dot2(A1.w,w0.w,a10);
            a11=dot2(A1.x,w1.x,a11); a11=dot2(A1.y,w1.y,a11); a11=dot2(A1.z,w1.z,a11); a11=dot2(A1.w,w1.w,a11);
            a12=dot2(A1.x,w2.x,a12); a12=dot2(A1.y,w2.y,a12); a12=dot2(A1.z,w2.z,a12); a12=dot2(A1.w,w2.w,a12);
            a13=dot2(A1.x,w3.x,a13); a13=dot2(A1.y,w3.y,a13); a13=dot2(A1.z,w3.z,a13); a13=dot2(A1.w,w3.w,a13);
        }
        s_h2[n0][j0]=a00; s_h2[n0][j0+1]=a01; s_h2[n0][j0+2]=a02; s_h2[n0][j0+3]=a03;
        s_h2[n0+1][j0]=a10; s_h2[n0+1][j0+1]=a11; s_h2[n0+1][j0+2]=a12; s_h2[n0+1][j0+3]=a13;
    }
    __syncthreads();

    // es/ed (single head) via 8-lane shuffle reduce
    {
        int n=t>>3, g=t&7;
        float e1=0,e2=0;
        #pragma unroll
        for(int cc=0; cc<8; cc++){
            float hv = s_h2[n][g*8+cc];
            e1 += hv*a_s2[g*8+cc];
            e2 += hv*a_d2[g*8+cc];
        }
        #pragma unroll
        for(int m=1;m<8;m<<=1){ e1 += __shfl_xor(e1,m,64); e2 += __shfl_xor(e2,m,64); }
        if(g==0){ s_es[n]=e1; s_ed[n]=e2; }
    }
    if(t==0){ int o=0; for(int i=0;i<NN;i++){ s_off[i]=o; o+=s_cnt[i]; } }
    __syncthreads();

    // CSR fill + edge-parallel logits + atomicMax
    for(int e=t;e<ETOT;e+=256){
        int d=s_dst[e]; int p=atomicAdd(&s_fil[d],1); s_lst[s_off[d]+p]=(short)e;
    }
    for(int e=t;e<ETOT;e+=256){
        int d=s_dst[e];
        float v = s_es[s_src[e]] + s_ed[d];
        v = v>0.f? v:0.2f*v;
        s_al[e]=v;
        atomicMax(&s_mx[d], fenc(v));
    }
    __syncthreads();

    for(int e=t;e<ETOT;e+=256){
        int d=s_dst[e];
        float p=__expf(s_al[e]-fdec(s_mx[d]));
        s_al[e]=p;
        atomicAdd(&s_sm[d], p);
    }
    __syncthreads();
    if(t<NN) s_inv[t]=1.f/(s_sm[t]+1e-16f);
    __syncthreads();

    // aggregate + scale + b2 + ELU + LayerNorm + transposed store [b][c][n]
    {
        int n=t>>3, g=t&7;
        float acc[8];
        #pragma unroll
        for(int i=0;i<8;i++) acc[i]=0;
        int o=s_off[n], cnt=s_cnt[n];
        float inv=s_inv[n];
        for(int i=0;i<cnt;i++){
            int e=s_lst[o+i]; float a=s_al[e]; int sr=s_src[e];
            const float4* hp=(const float4*)&s_h2[sr][g*8];
            float4 v0=hp[0], v1=hp[1];
            acc[0]+=a*v0.x; acc[1]+=a*v0.y; acc[2]+=a*v0.z; acc[3]+=a*v0.w;
            acc[4]+=a*v1.x; acc[5]+=a*v1.y; acc[6]+=a*v1.z; acc[7]+=a*v1.w;
        }
        float sum=0,sq=0;
        #pragma unroll
        for(int i=0;i<8;i++){
            float v = elu1(acc[i]*inv + b2[g*8+i]);
            acc[i]=v; sum+=v; sq+=v*v;
        }
        #pragma unroll
        for(int m=1;m<8;m<<=1){ sum+=__shfl_xor(sum,m,64); sq+=__shfl_xor(sq,m,64); }
        float mu = sum*(1.f/64.f);
        float var = sq*(1.f/64.f) - mu*mu;
        float rs = rsqrtf(var + 1e-5f);
        float* outp = hlng + (size_t)b*HID*NN;
        #pragma unroll
        for(int i=0;i<8;i++){
            int c=g*8+i;
            float v=(acc[i]-mu)*rs*gam[c] + bet[c];
            outp[c*NN + n] = v;
        }
    }
}

// --------------------------------- Fused GRU1+GRU2+FC, intra-wave k-split
// 256 threads = 4 waves. waves 0-1: GRU1 (units 0-31 / 32-63); waves 2-3: GRU2.
// Within a wave: lane = uu + 32*s  (uu = unit within block of 32, s = k-half).
// Partials combine via __shfl_xor(32); ONE barrier per step (h/y1 publish).
__global__ __launch_bounds__(256,2) void k_gruf(
    const float* __restrict__ hlng,
    const float* __restrict__ Wi1, const float* __restrict__ Wh1,
    const float* __restrict__ bi1, const float* __restrict__ bh1,
    const float* __restrict__ Wi2, const float* __restrict__ Wh2,
    const float* __restrict__ bi2, const float* __restrict__ bh2,
    const float* __restrict__ Wf, const float* __restrict__ bfv,
    void* __restrict__ outp, const int* __restrict__ flag)
{
    const int b=blockIdx.x, t=threadIdx.x;
    const int wave=t>>6, lane=t&63;
    const int layer=wave>>1;        // 0 = GRU1, 1 = GRU2
    const int ublk=wave&1;          // unit block (0: units 0-31, 1: units 32-63)
    const int uu=lane&31, s=lane>>5;
    const int u=ublk*32+uu;         // global hidden unit

    __shared__ __align__(16) u32 s_x1[64*16];   // GRU1 input fp16-packed [step][16]
    __shared__ __align__(16) u32 s_h1[2][32];   // h1 / y1 double buffer (64 f16)
    __shared__ __align__(16) u32 s_h2[2][32];   // h2 double buffer
    __shared__ float s_h2f[64];                 // final h2 fp32

    { const float2* g=(const float2*)(hlng + (size_t)b*2048);
      for(int w=t;w<1024;w+=256){ float2 v=g[w]; s_x1[w]=packf16(v.x,v.y); } }
    if(t<32){ s_h1[0][t]=0u; s_h1[1][t]=0u; s_h2[0][t]=0u; s_h2[1][t]=0u; }

    // per-lane packed half-row weights
    u32 wiR[16],wiZ[16],wiN[16],whR[16],whZ[16],whN[16];
    if(layer==0){
        const float2* WiF=(const float2*)Wi1;   // rows of 16 float2 (K=32)
        const float2* WhF=(const float2*)Wh1;   // rows of 32 float2 (K=64)
        #pragma unroll
        for(int k=0;k<8;k++){
            float2 a=WiF[u*16+s*8+k], c=WiF[(64+u)*16+s*8+k], d=WiF[(128+u)*16+s*8+k];
            wiR[k]=packf16(a.x,a.y); wiZ[k]=packf16(c.x,c.y); wiN[k]=packf16(d.x,d.y);
        }
        #pragma unroll
        for(int k=0;k<16;k++){
            float2 a=WhF[u*32+s*16+k], c=WhF[(64+u)*32+s*16+k], d=WhF[(128+u)*32+s*16+k];
            whR[k]=packf16(a.x,a.y); whZ[k]=packf16(c.x,c.y); whN[k]=packf16(d.x,d.y);
        }
    } else {
        const float2* WiF=(const float2*)Wi2;   // rows of 32 float2 (K=64)
        const float2* WhF=(const float2*)Wh2;
        #pragma unroll
        for(int k=0;k<16;k++){
            float2 a=WiF[u*32+s*16+k], c=WiF[(64+u)*32+s*16+k], d=WiF[(128+u)*32+s*16+k];
            wiR[k]=packf16(a.x,a.y); wiZ[k]=packf16(c.x,c.y); wiN[k]=packf16(d.x,d.y);
            float2 e=WhF[u*32+s*16+k], f=WhF[(64+u)*32+s*16+k], g2=WhF[(128+u)*32+s*16+k];
            whR[k]=packf16(e.x,e.y); whZ[k]=packf16(f.x,f.y); whN[k]=packf16(g2.x,g2.y);
        }
    }
    const float* bi = layer? bi2:bi1;
    const float* bh = layer? bh2:bh1;
    float br=bi[u]+bh[u], bz=bi[64+u]+bh[64+u], bxn=bi[128+u], bhn=bh[128+u];
    float h=0.f;
    __syncthreads();

    for(int it=0; it<=64; ++it){
        const int pb=(it-1)&1, cb=it&1;
        float pr=0.f,pz=0.f,pxn=0.f,phn=0.f;
        bool act;
        if(layer==0){
            act=(it<64);
            if(act){
                u32 xw[8], hw[16];
                const uint4* xp=(const uint4*)&s_x1[it*16+s*8];
                *(uint4*)&xw[0]=xp[0]; *(uint4*)&xw[4]=xp[1];
                const uint4* hp=(const uint4*)&s_h1[pb][s*16];
                #pragma unroll
                for(int q=0;q<4;q++) *(uint4*)&hw[q*4]=hp[q];
                #pragma unroll
                for(int k=0;k<8;k++){ pr=dot2(xw[k],wiR[k],pr); pz=dot2(xw[k],wiZ[k],pz); pxn=dot2(xw[k],wiN[k],pxn); }
                #pragma unroll
                for(int k=0;k<16;k++){ pr=dot2(hw[k],whR[k],pr); pz=dot2(hw[k],whZ[k],pz); phn=dot2(hw[k],whN[k],phn); }
            }
        } else {
            act=(it>=1);
            if(act){
                u32 xw[16], hw[16];
                const uint4* xp=(const uint4*)&s_h1[pb][s*16];   // y1[it-1]
                #pragma unroll
                for(int q=0;q<4;q++) *(uint4*)&xw[q*4]=xp[q];
                const uint4* hp=(const uint4*)&s_h2[pb][s*16];
                #pragma unroll
                for(int q=0;q<4;q++) *(uint4*)&hw[q*4]=hp[q];
                #pragma unroll
                for(int k=0;k<16;k++){
                    pr=dot2(xw[k],wiR[k],pr); pz=dot2(xw[k],wiZ[k],pz); pxn=dot2(xw[k],wiN[k],pxn);
                    pr=dot2(hw[k],whR[k],pr); pz=dot2(hw[k],whZ[k],pz); phn=dot2(hw[k],whN[k],phn);
                }
            }
        }
        if(act){
            // combine k-halves intra-wave (both halves end with full sums)
            pr  += __shfl_xor(pr ,32,64);
            pz  += __shfl_xor(pz ,32,64);
            pxn += __shfl_xor(pxn,32,64);
            phn += __shfl_xor(phn,32,64);
            float r=sigm(pr+br), z=sigm(pz+bz);
            float n=tanh_(pxn+bxn + r*(phn+bhn));
            h=(1.f-z)*n + z*h;
            if(s==0){
                u16 hv=f2h16(h);
                if(layer==0) ((u16*)s_h1[cb])[u]=hv;
                else { ((u16*)s_h2[cb])[u]=hv; if(it==64) s_h2f[u]=h; }
            }
        }
        __syncthreads();
    }

    if(t<OUT_CH){
        float acc=bfv[t];
        #pragma unroll
        for(int i=0;i<64;i++) acc += s_h2f[i]*Wf[t*64+i];
        if(*flag) ((float*)outp)[b*OUT_CH+t]=acc;
        else      ((u16*)outp)[b*OUT_CH+t]=f2bf(acc);
    }
}

extern "C" void kernel_launch(void* const* d_in, const int* in_sizes, int n_in,
                              void* d_out, int out_size, void* d_ws, size_t ws_size,
                              hipStream_t stream)
{
    char* ws=(char*)d_ws;
    int* flag = (int*)ws;
    float* cf = (float*)(ws + 256);
    float* c_x   = cf; cf+=196608;
    float* c_W1  = cf; cf+=6144;
    float* c_as1 = cf; cf+=512;
    float* c_ad1 = cf; cf+=512;
    float* c_b1  = cf; cf+=512;
    float* c_as2 = cf; cf+=64;
    float* c_ad2 = cf; cf+=64;
    float* c_b2  = cf; cf+=64;
    float* c_gam = cf; cf+=64;
    float* c_bet = cf; cf+=64;
    float* c_Wi1 = cf; cf+=6144;
    float* c_Wh1 = cf; cf+=12288;
    float* c_bi1 = cf; cf+=192;
    float* c_bh1 = cf; cf+=192;
    float* c_Wi2 = cf; cf+=12288;
    float* c_Wh2 = cf; cf+=12288;
    float* c_bi2 = cf; cf+=192;
    float* c_bh2 = cf; cf+=192;
    float* c_Wf  = cf; cf+=576;
    float* c_bf  = cf; cf+=9;
    uintptr_t p = ((uintptr_t)cf + 255) & ~(uintptr_t)255;
    u16* c_W2i = (u16*)p;                        // 32768 f16 = 64 KB (interleaved)
    p = (p + 32768*2 + 255) & ~(uintptr_t)255;
    u32* h1g = (u32*)p;                          // 512*32*256 u32 = 16.78 MB (fp16-packed)
    p = (p + (size_t)BATCH*NN*256*4 + 255) & ~(uintptr_t)255;
    float* hlng = (float*)p;                     // 512*64*32 f32 = 4.19 MB

    const int* ei = (const int*)d_in[1];

    CvtDesc d;
    const int srcIdx[20] = {0,2,3,4,5,7,8,9,10,11,12,13,14,15,16,17,18,19,20,21};
    void* dsts[20] = {c_x,c_W1,c_as1,c_ad1,c_b1,c_as2,c_ad2,c_b2,c_gam,c_bet,
                      c_Wi1,c_Wh1,c_bi1,c_bh1,c_Wi2,c_Wh2,c_bi2,c_bh2,c_Wf,c_bf};
    const int ns[20] = {196608,6144,512,512,512,64,64,64,64,64,
                        6144,12288,192,192,12288,12288,192,192,576,9};
    for(int i=0;i<20;i++){ d.src[i]=d_in[srcIdx[i]]; d.dst[i]=dsts[i]; d.n[i]=ns[i]; }

    k_detect <<<dim3(1),dim3(256),0,stream>>>((const u32*)d_in[0], flag);
    k_convert<<<dim3(20,8),dim3(256),0,stream>>>(d, flag);
    k_w2i    <<<dim3(128),dim3(256),0,stream>>>(d_in[6], c_W2i, flag);
    k_gat1   <<<dim3(BATCH),dim3(256),0,stream>>>(c_x,ei,c_W1,c_as1,c_ad1,c_b1,h1g);
    k_gat2ln <<<dim3(BATCH),dim3(256),0,stream>>>(h1g,ei,(const uint4*)c_W2i,c_as2,c_ad2,c_b2,c_gam,c_bet,hlng);
    k_gruf   <<<dim3(BATCH),dim3(256),0,stream>>>(hlng,c_Wi1,c_Wh1,c_bi1,c_bh1,
                                                  c_Wi2,c_Wh2,c_bi2,c_bh2,c_Wf,c_bf,d_out,flag);
}

// Round 7
// 258.740 us; speedup vs baseline: 1.4093x; 1.0047x over previous
//
#include <hip/hip_runtime.h>
#include <hip/hip_bf16.h>
#include <stdint.h>

#define BATCH 512
#define NN 32
#define T_IN 12
#define HID 64
#define HEADS 8
#define OUT_CH 9
#define EPB (NN*8)       // 256 edges per batch (before self loops)
#define ETOT (EPB+NN)    // 288 with self loops
#define F1 (HEADS*HID)   // 512

using u16 = unsigned short;
using u32 = unsigned int;
typedef _Float16 f16;
typedef _Float16 f16x2 __attribute__((ext_vector_type(2)));

__device__ __forceinline__ float bf2f(u16 u){ return __uint_as_float(((u32)u)<<16); }
__device__ __forceinline__ u16 f2bf(float f){
    u32 x = __float_as_uint(f);
    u32 r = (x + 0x7FFFu + ((x>>16)&1u))>>16;
    return (u16)r;
}
__device__ __forceinline__ u32 packf16(float a, float b){
    f16x2 p; p.x=(f16)a; p.y=(f16)b; return __builtin_bit_cast(u32,p);
}
__device__ __forceinline__ u16 f2h16(float a){ f16 h=(f16)a; return __builtin_bit_cast(u16,h); }
__device__ __forceinline__ float lof(u32 w){ return (float)__builtin_bit_cast(f16x2,w).x; }
__device__ __forceinline__ float hif(u32 w){ return (float)__builtin_bit_cast(f16x2,w).y; }
__device__ __forceinline__ float dot2(u32 a, u32 b, float c){
#if __has_builtin(__builtin_amdgcn_fdot2)
    return __builtin_amdgcn_fdot2(__builtin_bit_cast(f16x2,a), __builtin_bit_cast(f16x2,b), c, false);
#else
    return fmaf(lof(a),lof(b), fmaf(hif(a),hif(b), c));
#endif
}
__device__ __forceinline__ float elu1(float x){ return x > 0.f ? x : (__expf(x)-1.f); }
__device__ __forceinline__ float sigm(float x){ return 1.f/(1.f+__expf(-x)); }
__device__ __forceinline__ float tanh_(float x){ return 1.f - 2.f/(__expf(2.f*x)+1.f); }
// order-preserving float->u32 key for atomicMax
__device__ __forceinline__ u32 fenc(float v){
    u32 b=__float_as_uint(v);
    return (b&0x80000000u) ? ~b : (b|0x80000000u);
}
__device__ __forceinline__ float fdec(u32 k){
    return __uint_as_float((k&0x80000000u) ? (k&0x7FFFFFFFu) : ~k);
}

// ------------------------------------------------ dtype detection (fp32 vs bf16)
__global__ __launch_bounds__(256) void k_detect(const u32* __restrict__ xw, int* __restrict__ flag){
    __shared__ int cnt;
    if(threadIdx.x==0) cnt=0;
    __syncthreads();
    int c=0;
    for(int i=threadIdx.x;i<4096;i+=256){
        u32 w=xw[i];
        if(w & 0x7FFFFFFFu){
            u32 el=(w>>7)&0xFFu;
            if(el>=0x90u) c++;
        }
    }
    atomicAdd(&cnt,c);
    __syncthreads();
    if(threadIdx.x==0) *flag = (cnt>256) ? 1 : 0;   // 1 = fp32 inputs, 0 = bf16
}

// ------------------------------------------------ canonicalize inputs into ws (fp32)
struct CvtDesc {
    const void* src[16];
    void*       dst[16];
    int         n[16];
};

__global__ __launch_bounds__(256) void k_convert(CvtDesc d, const int* __restrict__ flag){
    const int seg = blockIdx.x;
    const int f = *flag;
    const void* s = d.src[seg];
    const int n = d.n[seg];
    const int stride = gridDim.y*256;
    float* o=(float*)d.dst[seg];
    for(int i=blockIdx.y*256+threadIdx.x;i<n;i+=stride)
        o[i] = f ? ((const float*)s)[i] : bf2f(((const u16*)s)[i]);
}

// W2 [512][64] -> interleaved fp16 W2i[(k>>3)*64+j][k&7]
__global__ __launch_bounds__(256) void k_w2i(const void* __restrict__ W2src, u16* __restrict__ W2i,
                                             const int* __restrict__ flag){
    int i = blockIdx.x*256+threadIdx.x;            // i = k*64+j
    int k=i>>6, j=i&63;
    float v = (*flag)? ((const float*)W2src)[i] : bf2f(((const u16*)W2src)[i]);
    W2i[ (((size_t)(k>>3)*64 + j)<<3) + (k&7) ] = f2h16(v);
}

// GRU weights -> packed fp16 [4 matrices][192 rows][32 u32 (K=64, Wi1 zero-padded)]
__global__ __launch_bounds__(256) void k_wpk(
    const void* __restrict__ Wi1, const void* __restrict__ Wh1,
    const void* __restrict__ Wi2, const void* __restrict__ Wh2,
    u32* __restrict__ wpk, const int* __restrict__ flag)
{
    int w = blockIdx.x*256+threadIdx.x;   // 0..24575
    int m = w/6144;
    int rem = w - m*6144;
    int row = rem>>5, kw = rem&31;
    const void* s = (m==0)?Wi1 : (m==1)?Wh1 : (m==2)?Wi2 : Wh2;
    int K = (m==0)?32:64;
    int f=*flag;
    int k0=2*kw, k1=k0+1;
    float v0=0.f, v1=0.f;
    if(k0<K) v0 = f? ((const float*)s)[row*K+k0] : bf2f(((const u16*)s)[row*K+k0]);
    if(k1<K) v1 = f? ((const float*)s)[row*K+k1] : bf2f(((const u16*)s)[row*K+k1]);
    wpk[w]=packf16(v0,v1);
}

// ---------------------------------------------------------------- GAT layer 1
__global__ __launch_bounds__(256,2) void k_gat1(
    const float* __restrict__ x, const int* __restrict__ ei,
    const float* __restrict__ W1, const float* __restrict__ a_s, const float* __restrict__ a_d,
    const float* __restrict__ b1, u32* __restrict__ h1g)
{
    const int b = blockIdx.x, t = threadIdx.x;
    __shared__ __align__(16) float s_x[NN][12];
    __shared__ float s_W1[T_IN*F1];
    __shared__ __align__(16) u16 s_h[NN][520];     // fp16, row pad 8 (16B-aligned rows)
    __shared__ u32 s_aspk[HEADS*32], s_adpk[HEADS*32];
    __shared__ float s_es[NN][HEADS], s_ed[NN][HEADS];
    __shared__ unsigned char s_src[ETOT], s_dst[ETOT];
    __shared__ float s_al[ETOT][HEADS];
    __shared__ u32 s_mx[NN*HEADS];
    __shared__ float s_sm[NN*HEADS], s_inv[NN*HEADS];
    __shared__ int s_cnt[NN], s_off[NN], s_fil[NN];
    __shared__ short s_lst[ETOT];

    for(int i=t;i<NN*T_IN;i+=256) s_x[i/12][i%12] = x[b*NN*T_IN + i];
    for(int i=t;i<T_IN*F1;i+=256) s_W1[i]=W1[i];
    s_aspk[t]=packf16(a_s[2*t],a_s[2*t+1]);
    s_adpk[t]=packf16(a_d[2*t],a_d[2*t+1]);
    s_mx[t]=0u; s_sm[t]=0.f;
    if(t<EPB){
        s_src[t] = (unsigned char)(ei[b*EPB+t] - b*NN);
        s_dst[t] = (unsigned char)(ei[(size_t)BATCH*EPB + b*EPB+t] - b*NN);
    }
    if(t<NN){ s_src[EPB+t]=s_dst[EPB+t]=(unsigned char)t; s_cnt[t]=0; s_fil[t]=0; }
    __syncthreads();

    // h = x @ W1 (pre-bias) -> LDS fp16 ; thread t owns columns t and t+256
    {
        float w0[12], w1[12];
        #pragma unroll
        for(int k=0;k<12;k++){ w0[k]=s_W1[k*F1+t]; w1[k]=s_W1[k*F1+t+256]; }
        for(int n=0;n<NN;n++){
            float xr[12];
            const float4* xp=(const float4*)s_x[n];
            *(float4*)&xr[0]=xp[0]; *(float4*)&xr[4]=xp[1]; *(float4*)&xr[8]=xp[2];
            float A=0.f,B=0.f;
            #pragma unroll
            for(int k=0;k<12;k++){ A=fmaf(xr[k],w0[k],A); B=fmaf(xr[k],w1[k],B); }
            s_h[n][t]=f2h16(A); s_h[n][t+256]=f2h16(B);
        }
    }
    for(int e=t;e<ETOT;e+=256) atomicAdd(&s_cnt[s_dst[e]],1);
    __syncthreads();

    // es/ed per (node, head) via fp16 dot2
    {
        int n=t&31, hd=t>>5;
        const uint4* hp=(const uint4*)((const u16*)s_h[n] + hd*64);
        u32 hw[32];
        #pragma unroll
        for(int q=0;q<8;q++) *(uint4*)&hw[q*4]=hp[q];
        float e1=0.f,e2=0.f;
        #pragma unroll
        for(int k=0;k<32;k++){ e1=dot2(hw[k],s_aspk[hd*32+k],e1); e2=dot2(hw[k],s_adpk[hd*32+k],e2); }
        s_es[n][hd]=e1; s_ed[n][hd]=e2;
    }
    if(t==0){ int o=0; for(int i=0;i<NN;i++){ s_off[i]=o; o+=s_cnt[i]; } }
    __syncthreads();

    // CSR fill (parallel) + edge-parallel logits + atomicMax
    for(int e=t;e<ETOT;e+=256){
        int d=s_dst[e]; int p=atomicAdd(&s_fil[d],1); s_lst[s_off[d]+p]=(short)e;
    }
    for(int i=t;i<ETOT*HEADS;i+=256){
        int e=i>>3, hd=i&7;
        int sr=s_src[e], d=s_dst[e];
        float v = s_es[sr][hd]+s_ed[d][hd];
        v = v>0.f? v : 0.2f*v;
        s_al[e][hd]=v;
        atomicMax(&s_mx[d*8+hd], fenc(v));
    }
    __syncthreads();

    // edge-parallel exp + sum
    for(int i=t;i<ETOT*HEADS;i+=256){
        int e=i>>3, hd=i&7;
        int d=s_dst[e];
        float p=__expf(s_al[e][hd]-fdec(s_mx[d*8+hd]));
        s_al[e][hd]=p;
        atomicAdd(&s_sm[d*8+hd], p);
    }
    __syncthreads();
    s_inv[t]=1.f/(s_sm[t]+1e-16f);
    __syncthreads();

    // aggregate (unscaled p), then scale by inv in epilogue; 2 column-chunks of 32
    {
        int d=t&31, hd=t>>5;
        int o=s_off[d], cnt=s_cnt[d];
        float inv=s_inv[d*8+hd];
        size_t obase = ((size_t)(b*NN+d))*256 + hd*32;
        #pragma unroll
        for(int ch=0;ch<2;ch++){
            float acc[32];
            #pragma unroll
            for(int i=0;i<32;i++) acc[i]=0.f;
            for(int i=0;i<cnt;i++){
                int e=s_lst[o+i]; float a=s_al[e][hd]; int sr=s_src[e];
                const uint4* hp=(const uint4*)((const u16*)s_h[sr] + hd*64 + ch*32);
                u32 pw[16];
                *(uint4*)&pw[0]=hp[0]; *(uint4*)&pw[4]=hp[1];
                *(uint4*)&pw[8]=hp[2]; *(uint4*)&pw[12]=hp[3];
                #pragma unroll
                for(int q=0;q<16;q++){ acc[2*q]+=a*lof(pw[q]); acc[2*q+1]+=a*hif(pw[q]); }
            }
            u32* op = h1g + obase + ch*16;
            #pragma unroll
            for(int j=0;j<16;j++){
                float v0=elu1(acc[2*j]*inv   + b1[hd*64+ch*32+2*j]);
                float v1=elu1(acc[2*j+1]*inv + b1[hd*64+ch*32+2*j+1]);
                op[j]=packf16(v0,v1);
            }
        }
    }
}

// --------------------------------------------- GAT layer 2 + LayerNorm (+transpose)
__global__ __launch_bounds__(256,2) void k_gat2ln(
    const u32* __restrict__ h1g, const int* __restrict__ ei,
    const uint4* __restrict__ W2i, const float* __restrict__ a_s2, const float* __restrict__ a_d2,
    const float* __restrict__ b2, const float* __restrict__ gam, const float* __restrict__ bet,
    float* __restrict__ hlng)
{
    const int b=blockIdx.x, t=threadIdx.x;
    __shared__ __align__(16) u32 s_h1[NN*260];   // fp16-packed rows, padded to 260 u32
    __shared__ float s_h2[NN][HID];
    __shared__ float s_es[NN], s_ed[NN];
    __shared__ unsigned char s_src[ETOT], s_dst[ETOT];
    __shared__ float s_al[ETOT];
    __shared__ u32 s_mx[NN];
    __shared__ float s_sm[NN], s_inv[NN];
    __shared__ int s_cnt[NN], s_off[NN], s_fil[NN];
    __shared__ short s_lst[ETOT];

    { const u32* g = h1g + (size_t)b*8192;
      for(int w=t; w<8192; w+=256){ int n=w>>8, c=w&255; s_h1[n*260+c]=g[w]; } }
    if(t<EPB){
        s_src[t]=(unsigned char)(ei[b*EPB+t]-b*NN);
        s_dst[t]=(unsigned char)(ei[(size_t)BATCH*EPB+b*EPB+t]-b*NN);
    }
    if(t<NN){ s_src[EPB+t]=s_dst[EPB+t]=(unsigned char)t;
              s_cnt[t]=0; s_fil[t]=0; s_mx[t]=0u; s_sm[t]=0.f; }
    __syncthreads();

    for(int e=t;e<ETOT;e+=256) atomicAdd(&s_cnt[s_dst[e]],1);
    // GEMM h2 = h1 @ W2 : 4 rows x 2 cols per thread (halves W2i L2 traffic)
    {
        int n0=(t>>5)<<2, j0=(t&31)<<1;
        const u32* r0=&s_h1[(n0+0)*260];
        const u32* r1=&s_h1[(n0+1)*260];
        const u32* r2=&s_h1[(n0+2)*260];
        const u32* r3=&s_h1[(n0+3)*260];
        float a00=0,a01=0,a10=0,a11=0,a20=0,a21=0,a30=0,a31=0;
        for(int kb=0;kb<64;kb++){
            uint4 A0=*(const uint4*)&r0[kb*4];
            uint4 A1=*(const uint4*)&r1[kb*4];
            uint4 A2=*(const uint4*)&r2[kb*4];
            uint4 A3=*(const uint4*)&r3[kb*4];
            const uint4* wp=&W2i[kb*64+j0];
            uint4 w0=wp[0], w1=wp[1];
            a00=dot2(A0.x,w0.x,a00); a00=dot2(A0.y,w0.y,a00); a00=dot2(A0.z,w0.z,a00); a00=dot2(A0.w,w0.w,a00);
            a01=dot2(A0.x,w1.x,a01); a01=dot2(A0.y,w1.y,a01); a01=dot2(A0.z,w1.z,a01); a01=dot2(A0.w,w1.w,a01);
            a10=dot2(A1.x,w0.x,a10); a10=dot2(A1.y,w0.y,a10); a10=dot2(A1.z,w0.z,a10); a10=dot2(A1.w,w0.w,a10);
            a11=dot2(A1.x,w1.x,a11); a11=dot2(A1.y,w1.y,a11); a11=dot2(A1.z,w1.z,a11); a11=dot2(A1.w,w1.w,a11);
            a20=dot2(A2.x,w0.x,a20); a20=dot2(A2.y,w0.y,a20); a20=dot2(A2.z,w0.z,a20); a20=dot2(A2.w,w0.w,a20);
            a21=dot2(A2.x,w1.x,a21); a21=dot2(A2.y,w1.y,a21); a21=dot2(A2.z,w1.z,a21); a21=dot2(A2.w,w1.w,a21);
            a30=dot2(A3.x,w0.x,a30); a30=dot2(A3.y,w0.y,a30); a30=dot2(A3.z,w0.z,a30); a30=dot2(A3.w,w0.w,a30);
            a31=dot2(A3.x,w1.x,a31); a31=dot2(A3.y,w1.y,a31); a31=dot2(A3.z,w1.z,a31); a31=dot2(A3.w,w1.w,a31);
        }
        s_h2[n0+0][j0]=a00; s_h2[n0+0][j0+1]=a01;
        s_h2[n0+1][j0]=a10; s_h2[n0+1][j0+1]=a11;
        s_h2[n0+2][j0]=a20; s_h2[n0+2][j0+1]=a21;
        s_h2[n0+3][j0]=a30; s_h2[n0+3][j0+1]=a31;
    }
    __syncthreads();

    // es/ed (single head) via 8-lane shuffle reduce
    {
        int n=t>>3, g=t&7;
        float e1=0,e2=0;
        #pragma unroll
        for(int cc=0; cc<8; cc++){
            float hv = s_h2[n][g*8+cc];
            e1 += hv*a_s2[g*8+cc];
            e2 += hv*a_d2[g*8+cc];
        }
        #pragma unroll
        for(int m=1;m<8;m<<=1){ e1 += __shfl_xor(e1,m,64); e2 += __shfl_xor(e2,m,64); }
        if(g==0){ s_es[n]=e1; s_ed[n]=e2; }
    }
    if(t==0){ int o=0; for(int i=0;i<NN;i++){ s_off[i]=o; o+=s_cnt[i]; } }
    __syncthreads();

    // CSR fill + edge-parallel logits + atomicMax
    for(int e=t;e<ETOT;e+=256){
        int d=s_dst[e]; int p=atomicAdd(&s_fil[d],1); s_lst[s_off[d]+p]=(short)e;
    }
    for(int e=t;e<ETOT;e+=256){
        int d=s_dst[e];
        float v = s_es[s_src[e]] + s_ed[d];
        v = v>0.f? v:0.2f*v;
        s_al[e]=v;
        atomicMax(&s_mx[d], fenc(v));
    }
    __syncthreads();

    for(int e=t;e<ETOT;e+=256){
        int d=s_dst[e];
        float p=__expf(s_al[e]-fdec(s_mx[d]));
        s_al[e]=p;
        atomicAdd(&s_sm[d], p);
    }
    __syncthreads();
    if(t<NN) s_inv[t]=1.f/(s_sm[t]+1e-16f);
    __syncthreads();

    // aggregate + scale + b2 + ELU + LayerNorm + transposed store [b][c][n]
    {
        int n=t>>3, g=t&7;
        float acc[8];
        #pragma unroll
        for(int i=0;i<8;i++) acc[i]=0;
        int o=s_off[n], cnt=s_cnt[n];
        float inv=s_inv[n];
        for(int i=0;i<cnt;i++){
            int e=s_lst[o+i]; float a=s_al[e]; int sr=s_src[e];
            const float4* hp=(const float4*)&s_h2[sr][g*8];
            float4 v0=hp[0], v1=hp[1];
            acc[0]+=a*v0.x; acc[1]+=a*v0.y; acc[2]+=a*v0.z; acc[3]+=a*v0.w;
            acc[4]+=a*v1.x; acc[5]+=a*v1.y; acc[6]+=a*v1.z; acc[7]+=a*v1.w;
        }
        float sum=0,sq=0;
        #pragma unroll
        for(int i=0;i<8;i++){
            float v = elu1(acc[i]*inv + b2[g*8+i]);
            acc[i]=v; sum+=v; sq+=v*v;
        }
        #pragma unroll
        for(int m=1;m<8;m<<=1){ sum+=__shfl_xor(sum,m,64); sq+=__shfl_xor(sq,m,64); }
        float mu = sum*(1.f/64.f);
        float var = sq*(1.f/64.f) - mu*mu;
        float rs = rsqrtf(var + 1e-5f);
        float* outp = hlng + (size_t)b*HID*NN;
        #pragma unroll
        for(int i=0;i<8;i++){
            int c=g*8+i;
            float v=(acc[i]-mu)*rs*gam[c] + bet[c];
            outp[c*NN + n] = v;
        }
    }
}

// --------------------------------- Fused GRU1+GRU2+FC, 4-way k-split, branch-free weights
// 512 threads = 8 waves. Waves 0-3: GRU1 units [w*16..w*16+15]; waves 4-7: GRU2.
// Lane = kq*16 + uu (kq = k-quarter 0..3, uu = unit-within-wave).
// All weights in regs (48 u32/lane), combine via shfl_xor(16)+shfl_xor(32), 1 barrier/step.
__global__ __launch_bounds__(512,1) void k_gruf(
    const float* __restrict__ hlng, const u32* __restrict__ wpk,
    const float* __restrict__ bi1, const float* __restrict__ bh1,
    const float* __restrict__ bi2, const float* __restrict__ bh2,
    const float* __restrict__ Wf, const float* __restrict__ bfv,
    void* __restrict__ outp, const int* __restrict__ flag)
{
    const int b=blockIdx.x, t=threadIdx.x;
    const int wave=t>>6, lane=t&63;
    const int layer=wave>>2;          // 0 = GRU1 waves, 1 = GRU2 waves
    const int uu=lane&15, kq=lane>>4; // unit-within-wave, k-quarter
    const int u=(wave&3)*16+uu;       // hidden unit 0..63

    __shared__ __align__(16) u32 s_x1[64][32];  // GRU1 input fp16, K zero-padded to 64
    __shared__ __align__(16) u32 s_h1[2][32];   // y1/h1 double buffer (64 f16)
    __shared__ __align__(16) u32 s_h2[2][32];   // h2 double buffer
    __shared__ float s_h2f[64];                 // final h2 fp32

    {   const float2* g=(const float2*)(hlng + (size_t)b*2048);
        for(int w=t;w<2048;w+=512){
            int step=w>>5, j=w&31;
            u32 v=0u;
            if(j<16){ float2 f=g[step*16+j]; v=packf16(f.x,f.y); }
            s_x1[step][j]=v;
        }
    }
    if(t<32){ s_h1[0][t]=0u; s_h1[1][t]=0u; s_h2[0][t]=0u; s_h2[1][t]=0u; }

    // straight-line weight init: 12 uint4 loads, no divergent control flow
    const u32* wi = wpk + (size_t)(layer*2+0)*6144 + kq*8;
    const u32* wh = wpk + (size_t)(layer*2+1)*6144 + kq*8;
    u32 wiR[8],wiZ[8],wiN[8],whR[8],whZ[8],whN[8];
    *(uint4*)&wiR[0]=*(const uint4*)&wi[(u     )*32];
    *(uint4*)&wiR[4]=*(const uint4*)&wi[(u     )*32+4];
    *(uint4*)&wiZ[0]=*(const uint4*)&wi[(64+u  )*32];
    *(uint4*)&wiZ[4]=*(const uint4*)&wi[(64+u  )*32+4];
    *(uint4*)&wiN[0]=*(const uint4*)&wi[(128+u )*32];
    *(uint4*)&wiN[4]=*(const uint4*)&wi[(128+u )*32+4];
    *(uint4*)&whR[0]=*(const uint4*)&wh[(u     )*32];
    *(uint4*)&whR[4]=*(const uint4*)&wh[(u     )*32+4];
    *(uint4*)&whZ[0]=*(const uint4*)&wh[(64+u  )*32];
    *(uint4*)&whZ[4]=*(const uint4*)&wh[(64+u  )*32+4];
    *(uint4*)&whN[0]=*(const uint4*)&wh[(128+u )*32];
    *(uint4*)&whN[4]=*(const uint4*)&wh[(128+u )*32+4];

    const float* bi = layer? bi2:bi1;
    const float* bh = layer? bh2:bh1;
    float br=bi[u]+bh[u], bz=bi[64+u]+bh[64+u], bxn=bi[128+u], bhn=bh[128+u];
    float h=0.f;
    __syncthreads();

    for(int it=0; it<=64; ++it){
        const int pb=(it-1)&1, cb=it&1;
        const bool act = layer ? (it>=1) : (it<64);
        if(act){
            u32 xw[8], hw[8];
            const uint4* xp = layer ? (const uint4*)&s_h1[pb][kq*8]
                                    : (const uint4*)&s_x1[it][kq*8];
            *(uint4*)&xw[0]=xp[0]; *(uint4*)&xw[4]=xp[1];
            const uint4* hp = layer ? (const uint4*)&s_h2[pb][kq*8]
                                    : (const uint4*)&s_h1[pb][kq*8];
            *(uint4*)&hw[0]=hp[0]; *(uint4*)&hw[4]=hp[1];
            float pr=0.f,pz=0.f,pxn=0.f,phn=0.f;
            #pragma unroll
            for(int k=0;k<8;k++){
                pr=dot2(xw[k],wiR[k],pr); pz=dot2(xw[k],wiZ[k],pz); pxn=dot2(xw[k],wiN[k],pxn);
                pr=dot2(hw[k],whR[k],pr); pz=dot2(hw[k],whZ[k],pz); phn=dot2(hw[k],whN[k],phn);
            }
            // combine 4 k-quarters (all lanes end with full sums)
            pr +=__shfl_xor(pr ,16,64); pz +=__shfl_xor(pz ,16,64);
            pxn+=__shfl_xor(pxn,16,64); phn+=__shfl_xor(phn,16,64);
            pr +=__shfl_xor(pr ,32,64); pz +=__shfl_xor(pz ,32,64);
            pxn+=__shfl_xor(pxn,32,64); phn+=__shfl_xor(phn,32,64);
            float r=sigm(pr+br), z=sigm(pz+bz);
            float n=tanh_(pxn+bxn + r*(phn+bhn));
            h=(1.f-z)*n + z*h;
            if(kq==0){
                u16 hv=f2h16(h);
                if(layer==0) ((u16*)s_h1[cb])[u]=hv;
                else { ((u16*)s_h2[cb])[u]=hv; if(it==64) s_h2f[u]=h; }
            }
        }
        __syncthreads();
    }

    if(t<OUT_CH){
        float acc=bfv[t];
        const float4* wp=(const float4*)(Wf + t*64);
        const float4* hp=(const float4*)s_h2f;
        #pragma unroll
        for(int k=0;k<16;k++){
            float4 w=wp[k], v=hp[k];
            acc += w.x*v.x + w.y*v.y + w.z*v.z + w.w*v.w;
        }
        if(*flag) ((float*)outp)[b*OUT_CH+t]=acc;
        else      ((u16*)outp)[b*OUT_CH+t]=f2bf(acc);
    }
}

extern "C" void kernel_launch(void* const* d_in, const int* in_sizes, int n_in,
                              void* d_out, int out_size, void* d_ws, size_t ws_size,
                              hipStream_t stream)
{
    char* ws=(char*)d_ws;
    int* flag = (int*)ws;
    float* cf = (float*)(ws + 256);
    float* c_x   = cf; cf+=196608;
    float* c_W1  = cf; cf+=6144;
    float* c_as1 = cf; cf+=512;
    float* c_ad1 = cf; cf+=512;
    float* c_b1  = cf; cf+=512;
    float* c_as2 = cf; cf+=64;
    float* c_ad2 = cf; cf+=64;
    float* c_b2  = cf; cf+=64;
    float* c_gam = cf; cf+=64;
    float* c_bet = cf; cf+=64;
    float* c_bi1 = cf; cf+=192;
    float* c_bh1 = cf; cf+=192;
    float* c_bi2 = cf; cf+=192;
    float* c_bh2 = cf; cf+=192;
    float* c_Wf  = cf; cf+=576;
    float* c_bf  = cf; cf+=9;
    uintptr_t p = ((uintptr_t)cf + 255) & ~(uintptr_t)255;
    u16* c_W2i = (u16*)p;                        // 32768 f16 = 64 KB (interleaved)
    p = (p + 32768*2 + 255) & ~(uintptr_t)255;
    u32* wpk = (u32*)p;                          // 4*192*32 u32 = 96 KB (packed GRU weights)
    p = (p + 24576*4 + 255) & ~(uintptr_t)255;
    u32* h1g = (u32*)p;                          // 512*32*256 u32 = 16.78 MB (fp16-packed)
    p = (p + (size_t)BATCH*NN*256*4 + 255) & ~(uintptr_t)255;
    float* hlng = (float*)p;                     // 512*64*32 f32 = 4.19 MB

    const int* ei = (const int*)d_in[1];

    CvtDesc d;
    const int srcIdx[16] = {0,2,3,4,5,7,8,9,10,11,14,15,18,19,20,21};
    void* dsts[16] = {c_x,c_W1,c_as1,c_ad1,c_b1,c_as2,c_ad2,c_b2,c_gam,c_bet,
                      c_bi1,c_bh1,c_bi2,c_bh2,c_Wf,c_bf};
    const int ns[16] = {196608,6144,512,512,512,64,64,64,64,64,
                        192,192,192,192,576,9};
    for(int i=0;i<16;i++){ d.src[i]=d_in[srcIdx[i]]; d.dst[i]=dsts[i]; d.n[i]=ns[i]; }

    k_detect <<<dim3(1),dim3(256),0,stream>>>((const u32*)d_in[0], flag);
    k_convert<<<dim3(16,8),dim3(256),0,stream>>>(d, flag);
    k_w2i    <<<dim3(128),dim3(256),0,stream>>>(d_in[6], c_W2i, flag);
    k_wpk    <<<dim3(96),dim3(256),0,stream>>>(d_in[12],d_in[13],d_in[16],d_in[17], wpk, flag);
    k_gat1   <<<dim3(BATCH),dim3(256),0,stream>>>(c_x,ei,c_W1,c_as1,c_ad1,c_b1,h1g);
    k_gat2ln <<<dim3(BATCH),dim3(256),0,stream>>>(h1g,ei,(const uint4*)c_W2i,c_as2,c_ad2,c_b2,c_gam,c_bet,hlng);
    k_gruf   <<<dim3(BATCH),dim3(512),0,stream>>>(hlng,wpk,c_bi1,c_bh1,c_bi2,c_bh2,c_Wf,c_bf,d_out,flag);
}